// Round 7
// baseline (4015.048 us; speedup 1.0000x reference)
//
#include <hip/hip_runtime.h>
#include <hip/hip_bf16.h>
#include <math.h>

#define H    1024
#define NST  64
#define LAYN 2
#define BSZ  32
#define TLEN 512
#define NSTEPS 16
#define H2   2048
#define DECBLK 256

typedef __attribute__((ext_vector_type(8))) short bf16x8;
typedef __attribute__((ext_vector_type(4))) float f32x4;

__device__ __forceinline__ float gelu_f(float x){
    return 0.5f*x*(1.0f+erff(x*0.7071067811865475f));
}
__device__ __forceinline__ float sigm_f(float x){
    return 1.0f/(1.0f+expf(-x));
}
__device__ __forceinline__ short bfbits(float x){
    __hip_bfloat16 h = __float2bfloat16(x);
    return *(short*)&h;
}
__device__ __forceinline__ void gload16(const void* g, void* l){
    __builtin_amdgcn_global_load_lds((const __attribute__((address_space(1))) void*)g,
                                     (__attribute__((address_space(3))) void*)l, 16, 0, 0);
}

// ---------------- discretized SSM params ----------------
__global__ void k_precompute(const float* __restrict__ log_dt,
                             const float* __restrict__ Are, const float* __restrict__ Aim,
                             const float* __restrict__ Bre, const float* __restrict__ Bim,
                             float* __restrict__ dAr, float* __restrict__ dAi,
                             float* __restrict__ dBr, float* __restrict__ dBi){
    int i = blockIdx.x*256 + threadIdx.x;
    if (i >= LAYN*H*NST) return;
    int lh = i / NST;
    float dt = expf(log_dt[lh]);
    float ar = Are[i], ai = Aim[i];
    float e  = expf(dt*ar);
    float sa, ca; sincosf(dt*ai, &sa, &ca);
    float dar = e*ca, dai = e*sa;
    float zr = dar-1.0f, zi = dai;
    float inv = 1.0f/(ar*ar + ai*ai);
    float wr = (zr*ar + zi*ai)*inv;
    float wi = (zi*ar - zr*ai)*inv;
    float br = Bre[i], bi = Bim[i];
    dAr[i]=dar; dAi[i]=dai;
    dBr[i]=wr*br - wi*bi;
    dBi[i]=wr*bi + wi*br;
}

// ---------------- in_proj ----------------
__global__ void k_inproj_x(const float* __restrict__ in, const float* __restrict__ w,
                           const float* __restrict__ bias, float* __restrict__ x){
    int i = blockIdx.x*256+threadIdx.x;          // b*T*H + t*H + h
    int h = i & (H-1);
    int bt = i >> 10;
    x[i] = in[bt]*w[h] + bias[h];
}
__global__ void k_inproj_xT(const float* __restrict__ in, const float* __restrict__ w,
                            const float* __restrict__ bias, float* __restrict__ xT){
    int i = blockIdx.x*256+threadIdx.x;          // b*H*T + h*T + t
    int t = i & (TLEN-1);
    int bh = i >> 9;
    int h = bh & (H-1);
    int b = bh >> 10;
    xT[i] = in[b*TLEN + t]*w[h] + bias[h];
}

// ---------------- S4 conv kernel gen ----------------
__global__ __launch_bounds__(64) void k_genK(
        const float* __restrict__ dAr, const float* __restrict__ dAi,
        const float* __restrict__ dBr, const float* __restrict__ dBi,
        const float* __restrict__ Cre, const float* __restrict__ Cim,
        float* __restrict__ Kbuf){
    __shared__ float trans[16][65];
    int lh = blockIdx.x;
    int lane = threadIdx.x;
    int pi = lh*NST + lane;
    float ar=dAr[pi], ai=dAi[pi];
    float br=dBr[pi], bi=dBi[pi];
    float cr=2.f*Cre[pi], ci=2.f*Cim[pi];
    float wr = cr*br - ci*bi;
    float wi = cr*bi + ci*br;
    float* Krow = Kbuf + (size_t)lh*TLEN;
    int r = lane>>2, q = lane&3;
    for (int c=0;c<TLEN/16;c++){
        #pragma unroll
        for (int i=0;i<16;i++){
            trans[i][lane] = wr;
            float nr = fmaf(wr,ar, -wi*ai);
            float ni = fmaf(wr,ai,  wi*ar);
            wr=nr; wi=ni;
        }
        __syncthreads();
        float s = 0.f;
        #pragma unroll
        for (int m=0;m<16;m++) s += trans[r][q*16+m];
        s += __shfl_xor(s,1,64);
        s += __shfl_xor(s,2,64);
        if (q==0) Krow[c*16 + r] = s;
        __syncthreads();
    }
}

// ---------------- causal Toeplitz conv + D*u + gelu; bf16 (B,H,T) out ----------------
#define CTT 256
#define CJT 64
__global__ __launch_bounds__(256) void k_conv(
        const float* __restrict__ u,            // (B,H,T) f32
        const float* __restrict__ Kbuf,         // (L,H,T)
        const float* __restrict__ Dv,
        __hip_bfloat16* __restrict__ g,         // (B,H,T) bf16
        int layer){
    __shared__ float u_s[CJT][33];
    __shared__ float Ks[CTT+CJT];
    int h  = blockIdx.y;
    int t0 = blockIdx.x * CTT;
    int tid = threadIdx.x;
    int bg = tid & 7;
    int tg = tid >> 3;
    const float* Krow = Kbuf + ((size_t)layer*H + h)*TLEN;
    float acc[8][4];
    #pragma unroll
    for (int i=0;i<8;i++){
        #pragma unroll
        for (int b=0;b<4;b++) acc[i][b]=0.f;
    }
    int ntile = t0/CJT + CTT/CJT;
    for (int jt=0; jt<ntile; jt++){
        int j0 = jt*CJT;
        __syncthreads();
        for (int i=tid; i<CTT+CJT; i+=256){
            int d = t0 - j0 - (CJT-1) + i;
            Ks[i] = (d>=0) ? Krow[d] : 0.f;
        }
        {
            int jj = tid & 63, bq = tid >> 6;
            #pragma unroll
            for (int p=0;p<8;p++){
                int b = bq + p*4;
                u_s[jj][b] = u[((size_t)b*H + h)*TLEN + j0 + jj];
            }
        }
        __syncthreads();
        #pragma unroll 8
        for (int j=0;j<CJT;j++){
            float4 ub = *(const float4*)&u_s[j][bg*4];
            int base = tg*8 + (CJT-1) - j;
            float kv[8];
            #pragma unroll
            for (int i=0;i<8;i++) kv[i] = Ks[base+i];
            #pragma unroll
            for (int i=0;i<8;i++){
                acc[i][0] = fmaf(kv[i], ub.x, acc[i][0]);
                acc[i][1] = fmaf(kv[i], ub.y, acc[i][1]);
                acc[i][2] = fmaf(kv[i], ub.z, acc[i][2]);
                acc[i][3] = fmaf(kv[i], ub.w, acc[i][3]);
            }
        }
    }
    float dv = Dv[layer*H + h];
    int tb = t0 + tg*8;
    #pragma unroll
    for (int b=0;b<4;b++){
        int bb = bg*4 + b;
        const float* urow = u + ((size_t)bb*H + h)*TLEN + tb;
        float4 u0 = *(const float4*)urow;
        float4 u1 = *(const float4*)(urow+4);
        bf16x8 o;
        o[0] = bfbits(gelu_f(fmaf(dv,u0.x, acc[0][b])));
        o[1] = bfbits(gelu_f(fmaf(dv,u0.y, acc[1][b])));
        o[2] = bfbits(gelu_f(fmaf(dv,u0.z, acc[2][b])));
        o[3] = bfbits(gelu_f(fmaf(dv,u0.w, acc[3][b])));
        o[4] = bfbits(gelu_f(fmaf(dv,u1.x, acc[4][b])));
        o[5] = bfbits(gelu_f(fmaf(dv,u1.y, acc[5][b])));
        o[6] = bfbits(gelu_f(fmaf(dv,u1.z, acc[6][b])));
        o[7] = bfbits(gelu_f(fmaf(dv,u1.w, acc[7][b])));
        *(bf16x8*)(g + ((size_t)bb*H + h)*TLEN + tb) = o;
    }
}

// ---------------- bf16 transpose (B,H,T) -> (B,T,H) ----------------
__global__ __launch_bounds__(256) void k_trcast_bf(const __hip_bfloat16* __restrict__ x,
                                                   __hip_bfloat16* __restrict__ y){
    __shared__ __hip_bfloat16 tile[32][34];
    int t0 = blockIdx.x*32, h0 = blockIdx.y*32, b = blockIdx.z;
    int tx = threadIdx.x & 31, ty = threadIdx.x >> 5;
    #pragma unroll
    for (int i=0;i<32;i+=8)
        tile[ty+i][tx] = x[((size_t)(b*H + h0+ty+i))*TLEN + t0+tx];
    __syncthreads();
    #pragma unroll
    for (int i=0;i<32;i+=8)
        y[((size_t)(b*TLEN + t0+ty+i))*H + h0+tx] = tile[tx][ty+i];
}

// ---------------- W (L,H,2H) f32 -> Wt (L,2H,H) bf16 (encoder GEMM B operand) ----------------
__global__ __launch_bounds__(256) void k_wtr(const float* __restrict__ W,
                                             __hip_bfloat16* __restrict__ Wt){
    __shared__ float tile[32][33];
    int n0 = blockIdx.x*32, k0 = blockIdx.y*32, l = blockIdx.z;
    const float* Wl = W + (size_t)l*H*H2;
    __hip_bfloat16* Wtl = Wt + (size_t)l*H*H2;
    int tx = threadIdx.x & 31, ty = threadIdx.x >> 5;
    #pragma unroll
    for (int i=0;i<32;i+=8)
        tile[ty+i][tx] = Wl[(size_t)(k0+ty+i)*H2 + n0+tx];
    __syncthreads();
    #pragma unroll
    for (int i=0;i<32;i+=8)
        Wtl[(size_t)(n0+ty+i)*H + k0+tx] = __float2bfloat16(tile[tx][ty+i]);
}

// ---------------- W (L,H,2H) f32 -> Wdt (L,2H,H) f32 (decode GEMM rows) ----------------
__global__ __launch_bounds__(256) void k_wtrf(const float* __restrict__ W,
                                              float* __restrict__ Wdt){
    __shared__ float tile[32][33];
    int n0 = blockIdx.x*32, k0 = blockIdx.y*32, l = blockIdx.z;
    const float* Wl = W + (size_t)l*H*H2;
    float* Wo = Wdt + (size_t)l*H2*H;
    int tx = threadIdx.x & 31, ty = threadIdx.x >> 5;
    #pragma unroll
    for (int i=0;i<32;i+=8)
        tile[ty+i][tx] = Wl[(size_t)(k0+ty+i)*H2 + n0+tx];
    __syncthreads();
    #pragma unroll
    for (int i=0;i<32;i+=8)
        Wo[(size_t)(n0+ty+i)*H + k0+tx] = tile[tx][ty+i];
}

// ---------------- bf16 MFMA GEMM + bias + GLU fused (encoder) ----------------
__global__ __launch_bounds__(256) void k_gemm_glu_mfma(
        const __hip_bfloat16* __restrict__ Abf,
        const __hip_bfloat16* __restrict__ Wt,
        const float* __restrict__ bias2,         // (2048,)
        float* __restrict__ glu){                // (M,1024)
    __shared__ alignas(16) short As[128*32];
    __shared__ alignas(16) short Bs[128*32];
    const int K = 1024;
    int tid = threadIdx.x;
    int lane = tid & 63, wid = tid >> 6;
    int m0 = blockIdx.x * 128;
    int nb = blockIdx.y * 64;
    int g0 = tid, g1 = tid + 256;
    int r0 = g0 >> 2, r1 = g1 >> 2;
    int wtr0 = nb + ((r0>>6)<<5) + (r0&31) + ((r0>>5)&1)*1024;
    int wtr1 = nb + ((r1>>6)<<5) + (r1&31) + ((r1>>5)&1)*1024;
    const short* Ap = (const short*)Abf;
    const short* Bp = (const short*)Wt;
    const short* Ag0 = Ap + (size_t)(m0 + r0)*K + (g0&3)*8;
    const short* Ag1 = Ap + (size_t)(m0 + r1)*K + (g1&3)*8;
    const short* Bg0 = Bp + (size_t)wtr0*K + (g0&3)*8;
    const short* Bg1 = Bp + (size_t)wtr1*K + (g1&3)*8;
    char* AsB = (char*)As;
    char* BsB = (char*)Bs;
    int wr = wid >> 1, wc = wid & 1;
    int mo = wr*64, no = wc*64;
    f32x4 acc[4][4] = {};
    int arow = (lane & 15)*32 + (lane>>4)*8;
    for (int k0 = 0; k0 < K; k0 += 32){
        gload16(Ag0 + k0, AsB + wid*1024);
        gload16(Ag1 + k0, AsB + 4096 + wid*1024);
        gload16(Bg0 + k0, BsB + wid*1024);
        gload16(Bg1 + k0, BsB + 4096 + wid*1024);
        asm volatile("s_waitcnt vmcnt(0)" ::: "memory");
        __syncthreads();
        bf16x8 a[4], b[4];
        #pragma unroll
        for (int mi=0;mi<4;mi++)
            a[mi] = *(const bf16x8*)(As + (mo + mi*16)*32 + arow);
        #pragma unroll
        for (int ni=0;ni<4;ni++)
            b[ni] = *(const bf16x8*)(Bs + (no + ni*16)*32 + arow);
        #pragma unroll
        for (int mi=0;mi<4;mi++){
            #pragma unroll
            for (int ni=0;ni<4;ni++){
                acc[mi][ni] = __builtin_amdgcn_mfma_f32_16x16x32_bf16(a[mi], b[ni], acc[mi][ni], 0, 0, 0);
            }
        }
        __syncthreads();
    }
    int cbase = nb + wc*32 + (lane&15);
    #pragma unroll
    for (int ni=0;ni<2;ni++){
        int c = cbase + ni*16;
        float ba = bias2[c], bb = bias2[c+1024];
        #pragma unroll
        for (int mi=0;mi<4;mi++){
            #pragma unroll
            for (int r=0;r<4;r++){
                size_t m = m0 + mo + mi*16 + (lane>>4)*4 + r;
                float za = acc[mi][ni][r] + ba;
                float zb = acc[mi][ni+2][r] + bb;
                glu[m*H + c] = za * sigm_f(zb);
            }
        }
    }
}

// ---------------- LayerNorm over H per (b,t) row (encoder) ----------------
__global__ __launch_bounds__(256) void k_ln(const float* __restrict__ glu, const float* __restrict__ res,
        const float* __restrict__ gamma, const float* __restrict__ beta, float* __restrict__ outx){
    __shared__ float red[8];
    int row = blockIdx.x;
    int tid = threadIdx.x;
    float4 gv = *(const float4*)(glu + (size_t)row*H + tid*4);
    float4 rv = *(const float4*)(res + (size_t)row*H + tid*4);
    float x0=gv.x+rv.x, x1=gv.y+rv.y, x2=gv.z+rv.z, x3=gv.w+rv.w;
    float s = x0+x1+x2+x3;
    float q = x0*x0+x1*x1+x2*x2+x3*x3;
    #pragma unroll
    for (int m=32;m>=1;m>>=1){ s += __shfl_xor(s,m,64); q += __shfl_xor(q,m,64); }
    int wv = tid>>6;
    if ((tid&63)==0){ red[wv]=s; red[4+wv]=q; }
    __syncthreads();
    s = red[0]+red[1]+red[2]+red[3];
    q = red[4]+red[5]+red[6]+red[7];
    float m = s*(1.0f/H);
    float v = q*(1.0f/H) - m*m;
    float rstd = rsqrtf(v + 1e-5f);
    float4 gm = *(const float4*)(gamma + tid*4);
    float4 bt = *(const float4*)(beta + tid*4);
    float4 o;
    o.x = (x0-m)*rstd*gm.x + bt.x;
    o.y = (x1-m)*rstd*gm.y + bt.y;
    o.z = (x2-m)*rstd*gm.z + bt.z;
    o.w = (x3-m)*rstd*gm.w + bt.w;
    *(float4*)(outx + (size_t)row*H + tid*4) = o;
}

// ---------------- transpose (b,t,h) -> (b,h,t) f32 ----------------
__global__ __launch_bounds__(256) void k_transpose(const float* __restrict__ x, float* __restrict__ xT){
    __shared__ float tile[32][33];
    int t0 = blockIdx.x*32, h0 = blockIdx.y*32, b = blockIdx.z;
    int tx = threadIdx.x & 31, ty = threadIdx.x >> 5;
    #pragma unroll
    for (int i=0;i<32;i+=8)
        tile[ty+i][tx] = x[((size_t)(b*TLEN + t0+ty+i))*H + h0+tx];
    __syncthreads();
    #pragma unroll
    for (int i=0;i<32;i+=8)
        xT[((size_t)(b*H + h0+ty+i))*TLEN + t0+tx] = tile[tx][ty+i];
}

__global__ void k_ctx(const float* __restrict__ x, float* __restrict__ ctx){
    int i = blockIdx.x*256+threadIdx.x;
    int b = i>>10, h = i&(H-1);
    ctx[i] = x[((size_t)(b*TLEN + TLEN-1))*H + h];
}

// ======================= PERSISTENT DECODE =======================
// 256 blocks x 256 threads, regular launch (graph-capture safe).
// Global barrier: one counter per barrier event, memset to 0 each launch.
__device__ __forceinline__ void gbar(int* cnt, int tid){
    __syncthreads();
    if (tid == 0){
        __threadfence();
        __hip_atomic_fetch_add(cnt, 1, __ATOMIC_RELEASE, __HIP_MEMORY_SCOPE_AGENT);
        int it = 0;
        while (__hip_atomic_load(cnt, __ATOMIC_RELAXED, __HIP_MEMORY_SCOPE_AGENT) < DECBLK){
            __builtin_amdgcn_s_sleep(2);
            if (++it > 2000000) break;   // ~1s escape: broken barrier -> wrong answer, not a hang
        }
        __threadfence();
    }
    __syncthreads();
}

// decode GEMM phase: blocks 0..127, p = blk*8 + (tid>>5) in [0,1024), b = tid&31.
// u staged in LDS quarters; W rows contiguous f32 (Wdt).
__device__ __forceinline__ void dec_gemm_p(int blk, int tid, float (*u_s)[260],
        const float* __restrict__ ygel, const float* __restrict__ Wdt,
        const float* __restrict__ b2, float* __restrict__ glud){
    int p = blk*8 + (tid>>5);
    int b = tid & 31;
    const float* wa = Wdt + (size_t)p*H;
    const float* wb = Wdt + (size_t)(p+1024)*H;
    float aa=0.f, ab=0.f;
    int row = tid & 31, cc = (tid>>5)*4;
    for (int kq=0; kq<4; kq++){
        __syncthreads();
        #pragma unroll
        for (int i=0;i<8;i++){
            int col = cc + i*32;
            *(float4*)&u_s[row][col] = *(const float4*)&ygel[row*H + kq*256 + col];
        }
        __syncthreads();
        const float* wak = wa + kq*256;
        const float* wbk = wb + kq*256;
        #pragma unroll 8
        for (int k=0;k<256;k+=8){
            float4 u0 = *(const float4*)&u_s[b][k];
            float4 u1 = *(const float4*)&u_s[b][k+4];
            float4 wa0 = *(const float4*)(wak + k);
            float4 wa1 = *(const float4*)(wak + k + 4);
            float4 wb0 = *(const float4*)(wbk + k);
            float4 wb1 = *(const float4*)(wbk + k + 4);
            aa = fmaf(u0.x,wa0.x, fmaf(u0.y,wa0.y, fmaf(u0.z,wa0.z, fmaf(u0.w,wa0.w, aa))));
            aa = fmaf(u1.x,wa1.x, fmaf(u1.y,wa1.y, fmaf(u1.z,wa1.z, fmaf(u1.w,wa1.w, aa))));
            ab = fmaf(u0.x,wb0.x, fmaf(u0.y,wb0.y, fmaf(u0.z,wb0.z, fmaf(u0.w,wb0.w, ab))));
            ab = fmaf(u1.x,wb1.x, fmaf(u1.y,wb1.y, fmaf(u1.z,wb1.z, fmaf(u1.w,wb1.w, ab))));
        }
    }
    glud[b*H + p] = (aa + b2[p]) * sigm_f(ab + b2[p+H]);
}

__device__ __forceinline__ void dec_ln_phase(int b, int tid, float* red,
        const float* __restrict__ glud, const float* __restrict__ gamma,
        const float* __restrict__ beta, float* __restrict__ decout,
        const float* __restrict__ ctx, const float* __restrict__ headw,
        const float* __restrict__ headb, float* __restrict__ bits,
        float* __restrict__ out, int step, int last){
    float4 gv = *(const float4*)(glud + (size_t)b*H + tid*4);
    float x0,x1,x2,x3;
    if (step==0){ x0=gv.x; x1=gv.y; x2=gv.z; x3=gv.w; }           // res = u0 = 0
    else        { x0=2.f*gv.x; x1=2.f*gv.y; x2=2.f*gv.z; x3=2.f*gv.w; }  // res = y
    float s = x0+x1+x2+x3, q = x0*x0+x1*x1+x2*x2+x3*x3;
    #pragma unroll
    for (int m=32;m>=1;m>>=1){ s+=__shfl_xor(s,m,64); q+=__shfl_xor(q,m,64); }
    int wv = tid>>6;
    if ((tid&63)==0){ red[wv]=s; red[4+wv]=q; }
    __syncthreads();
    s = red[0]+red[1]+red[2]+red[3];
    q = red[4]+red[5]+red[6]+red[7];
    float m = s*(1.f/H), v = q*(1.f/H)-m*m, rstd = rsqrtf(v+1e-5f);
    float4 gm = *(const float4*)(gamma + tid*4);
    float4 bt = *(const float4*)(beta + tid*4);
    float d0 = (x0-m)*rstd*gm.x+bt.x;
    float d1 = (x1-m)*rstd*gm.y+bt.y;
    float d2 = (x2-m)*rstd*gm.z+bt.z;
    float d3 = (x3-m)*rstd*gm.w+bt.w;
    if (!last){
        float4 o; o.x=d0;o.y=d1;o.z=d2;o.w=d3;
        *(float4*)(decout + (size_t)b*H + tid*4) = o;
    } else {
        float4 cv = *(const float4*)(ctx + (size_t)b*H + tid*4);
        d0+=cv.x; d1+=cv.y; d2+=cv.z; d3+=cv.w;
        float4 hw = *(const float4*)(headw + tid*4);
        float hp = d0*hw.x + d1*hw.y + d2*hw.z + d3*hw.w;
        #pragma unroll
        for (int mm=32;mm>=1;mm>>=1) hp += __shfl_xor(hp,mm,64);
        __syncthreads();
        if ((tid&63)==0) red[wv]=hp;
        __syncthreads();
        if (tid==0){
            float hs = red[0]+red[1]+red[2]+red[3] + headb[0];
            float bit = sigm_f(hs);
            bits[b] = bit;
            out[b*NSTEPS + step] = bit;
        }
    }
}

__global__ __launch_bounds__(256, 1) void k_decode(
        const float* __restrict__ dAr, const float* __restrict__ dAi,
        const float* __restrict__ dBr, const float* __restrict__ dBi,
        const float* __restrict__ Cre, const float* __restrict__ Cim,
        const float* __restrict__ Dv,
        const float* __restrict__ Wdt, const float* __restrict__ bias2,
        const float* __restrict__ lng, const float* __restrict__ lnb,
        const float* __restrict__ ctx, const float* __restrict__ headw,
        const float* __restrict__ headb,
        float* __restrict__ ygel, float* __restrict__ glud,
        float* __restrict__ dec, float* __restrict__ bits,
        float* __restrict__ out, int* __restrict__ bar){
    __shared__ float u_s[32][260];
    __shared__ float red[8];
    int blk = blockIdx.x, tid = threadIdx.x;
    int gtid = blk*256 + tid;
    int pair = gtid >> 1, half = gtid & 1;   // pair = b*H + h
    int pb = pair >> 10, ph = pair & 1023;
    float s0r[32], s0i[32], s1r[32], s1i[32];
    #pragma unroll
    for (int j=0;j<32;j++){ s0r[j]=0.f; s0i[j]=0.f; s1r[j]=0.f; s1i[j]=0.f; }
    int bidx = 0;
    for (int step=0; step<NSTEPS; step++){
        // ---- layer 0 state: thread owns 32 states of (pair, half)
        {
            float u = (step==0) ? 0.f : bits[pb];
            int p0 = ph*NST + half*32;
            float c = 0.f;
            #pragma unroll
            for (int j=0;j<32;j++){
                float ar=dAr[p0+j], ai=dAi[p0+j], br=dBr[p0+j], bj=dBi[p0+j];
                float nr = fmaf(ar,s0r[j], fmaf(-ai,s0i[j], br*u));
                float ni = fmaf(ai,s0r[j], fmaf( ar,s0i[j], bj*u));
                s0r[j]=nr; s0i[j]=ni;
                c = fmaf(Cre[p0+j], nr, fmaf(-Cim[p0+j], ni, c));
            }
            c += __shfl_xor(c, 1, 64);
            if (!half) ygel[pair] = gelu_f(2.f*c + Dv[ph]*u);
        }
        gbar(bar + bidx++, tid);
        if (blk < 128) dec_gemm_p(blk, tid, u_s, ygel, Wdt, bias2, glud);
        gbar(bar + bidx++, tid);
        if (blk < 32) dec_ln_phase(blk, tid, red, glud, lng, lnb, dec,
                                   ctx, headw, headb, bits, out, step, 0);
        gbar(bar + bidx++, tid);
        // ---- layer 1 state (u = dec)
        {
            float u = dec[pair];
            int p1 = (H + ph)*NST + half*32;
            float c = 0.f;
            #pragma unroll
            for (int j=0;j<32;j++){
                float ar=dAr[p1+j], ai=dAi[p1+j], br=dBr[p1+j], bj=dBi[p1+j];
                float nr = fmaf(ar,s1r[j], fmaf(-ai,s1i[j], br*u));
                float ni = fmaf(ai,s1r[j], fmaf( ar,s1i[j], bj*u));
                s1r[j]=nr; s1i[j]=ni;
                c = fmaf(Cre[p1+j], nr, fmaf(-Cim[p1+j], ni, c));
            }
            c += __shfl_xor(c, 1, 64);
            if (!half) ygel[pair] = gelu_f(2.f*c + Dv[H+ph]*u);
        }
        gbar(bar + bidx++, tid);
        if (blk < 128) dec_gemm_p(blk, tid, u_s, ygel, Wdt + (size_t)H2*H, bias2 + H2, glud);
        gbar(bar + bidx++, tid);
        if (blk < 32) dec_ln_phase(blk, tid, red, glud, lng+H, lnb+H, dec,
                                   ctx, headw, headb, bits, out, step, 1);
        gbar(bar + bidx++, tid);
    }
}

extern "C" void kernel_launch(void* const* d_in, const int* in_sizes, int n_in,
                              void* d_out, int out_size, void* d_ws, size_t ws_size,
                              hipStream_t stream) {
    const float* in_seq = (const float*)d_in[0];
    const float* inw  = (const float*)d_in[2];
    const float* inb  = (const float*)d_in[3];
    const float* log_dt = (const float*)d_in[4];
    const float* Are = (const float*)d_in[5];
    const float* Aim = (const float*)d_in[6];
    const float* Bre = (const float*)d_in[7];
    const float* Bim = (const float*)d_in[8];
    const float* Cre = (const float*)d_in[9];
    const float* Cim = (const float*)d_in[10];
    const float* Dv  = (const float*)d_in[11];
    const float* outw = (const float*)d_in[12];
    const float* outb = (const float*)d_in[13];
    const float* lng = (const float*)d_in[14];
    const float* lnb = (const float*)d_in[15];
    const float* headw = (const float*)d_in[16];
    const float* headb = (const float*)d_in[17];
    float* out = (float*)d_out;

    float* ws = (float*)d_ws;
    size_t off = 0;
    auto alloc = [&](size_t n){ float* p = ws + off; off += n; return p; };
    float* dAr = alloc((size_t)LAYN*H*NST);
    float* dAi = alloc((size_t)LAYN*H*NST);
    float* dBr = alloc((size_t)LAYN*H*NST);
    float* dBi = alloc((size_t)LAYN*H*NST);
    float* Kbuf = alloc((size_t)LAYN*H*TLEN);
    float* bufA = alloc((size_t)BSZ*TLEN*H);                              // 67MB
    float* bufB = alloc((size_t)BSZ*TLEN*H);                              // 67MB
    __hip_bfloat16* gbf = (__hip_bfloat16*)alloc((size_t)BSZ*TLEN*H/2);   // 33.5MB
    float* ctx = alloc((size_t)BSZ*H);
    float* sre = alloc((size_t)LAYN*BSZ*H*NST);                           // 16.8MB
    float* sim = alloc((size_t)LAYN*BSZ*H*NST);                           // 16.8MB
    __hip_bfloat16* Abf = (__hip_bfloat16*)sre;  // alias: Abf dead before decode
    __hip_bfloat16* Wt  = (__hip_bfloat16*)alloc((size_t)LAYN*H*H2/2);    // 8.4MB
    float* Wdt = alloc((size_t)LAYN*H2*H);                                // 16.8MB
    float* ygel = alloc((size_t)BSZ*H);
    float* glud = alloc((size_t)BSZ*H);
    float* dec  = alloc((size_t)BSZ*H);
    float* bits = alloc(64);
    int*   bar  = (int*)alloc(128);
    // total ~233 MB (round-3's proven 241.7 MB OK; round-4's 283.6 MB crashed)

    k_precompute<<<(LAYN*H*NST+255)/256, 256, 0, stream>>>(log_dt,Are,Aim,Bre,Bim,dAr,dAi,dBr,dBi);
    k_genK<<<LAYN*H, 64, 0, stream>>>(dAr,dAi,dBr,dBi,Cre,Cim,Kbuf);
    k_wtr<<<dim3(H2/32, H/32, LAYN), 256, 0, stream>>>(outw, Wt);
    k_wtrf<<<dim3(H2/32, H/32, LAYN), 256, 0, stream>>>(outw, Wdt);
    k_inproj_x <<<(BSZ*TLEN*H)/256, 256, 0, stream>>>(in_seq, inw, inb, bufA);
    k_inproj_xT<<<(BSZ*TLEN*H)/256, 256, 0, stream>>>(in_seq, inw, inb, bufB);

    // ---- layer 0: res = bufA (b,t,h); xT = bufB (b,h,t)
    k_conv<<<dim3(TLEN/CTT, H), 256, 0, stream>>>(bufB, Kbuf, Dv, gbf, 0);
    k_trcast_bf<<<dim3(TLEN/32, H/32, BSZ), 256, 0, stream>>>(gbf, Abf);
    k_gemm_glu_mfma<<<dim3(BSZ*TLEN/128, H/64), 256, 0, stream>>>(Abf, Wt, outb, bufB);
    k_ln<<<BSZ*TLEN, 256, 0, stream>>>(bufB, bufA, lng, lnb, bufA);
    k_transpose<<<dim3(16,32,32), 256, 0, stream>>>(bufA, bufB);

    // ---- layer 1
    k_conv<<<dim3(TLEN/CTT, H), 256, 0, stream>>>(bufB, Kbuf, Dv, gbf, 1);
    k_trcast_bf<<<dim3(TLEN/32, H/32, BSZ), 256, 0, stream>>>(gbf, Abf);
    k_gemm_glu_mfma<<<dim3(BSZ*TLEN/128, H/64), 256, 0, stream>>>(Abf, Wt + (size_t)H*H2, outb + H2, bufB);
    k_ln<<<BSZ*TLEN, 256, 0, stream>>>(bufB, bufA, lng+H, lnb+H, bufA);

    k_ctx<<<(BSZ*H)/256, 256, 0, stream>>>(bufA, ctx);

    // ---- decode: one persistent kernel, 96 software grid barriers
    hipMemsetAsync(bar, 0, sizeof(int)*128, stream);
    k_decode<<<DECBLK, 256, 0, stream>>>(dAr,dAi,dBr,dBi,Cre,Cim,Dv,
                                         Wdt, outb, lng, lnb, ctx, headw, headb,
                                         ygel, glud, dec, bits, out, bar);
}

// Round 8
// 3335.179 us; speedup vs baseline: 1.2038x; 1.2038x over previous
//
#include <hip/hip_runtime.h>
#include <hip/hip_bf16.h>
#include <math.h>

#define H    1024
#define NST  64
#define LAYN 2
#define BSZ  32
#define TLEN 512
#define NSTEPS 16
#define H2   2048
#define DECBLK 256

typedef __attribute__((ext_vector_type(8))) short bf16x8;
typedef __attribute__((ext_vector_type(4))) float f32x4;

__device__ __forceinline__ float gelu_f(float x){
    return 0.5f*x*(1.0f+erff(x*0.7071067811865475f));
}
__device__ __forceinline__ float sigm_f(float x){
    return 1.0f/(1.0f+expf(-x));
}
__device__ __forceinline__ short bfbits(float x){
    __hip_bfloat16 h = __float2bfloat16(x);
    return *(short*)&h;
}
__device__ __forceinline__ void gload16(const void* g, void* l){
    __builtin_amdgcn_global_load_lds((const __attribute__((address_space(1))) void*)g,
                                     (__attribute__((address_space(3))) void*)l, 16, 0, 0);
}

// ---------------- discretized SSM params ----------------
__global__ void k_precompute(const float* __restrict__ log_dt,
                             const float* __restrict__ Are, const float* __restrict__ Aim,
                             const float* __restrict__ Bre, const float* __restrict__ Bim,
                             float* __restrict__ dAr, float* __restrict__ dAi,
                             float* __restrict__ dBr, float* __restrict__ dBi){
    int i = blockIdx.x*256 + threadIdx.x;
    if (i >= LAYN*H*NST) return;
    int lh = i / NST;
    float dt = expf(log_dt[lh]);
    float ar = Are[i], ai = Aim[i];
    float e  = expf(dt*ar);
    float sa, ca; sincosf(dt*ai, &sa, &ca);
    float dar = e*ca, dai = e*sa;
    float zr = dar-1.0f, zi = dai;
    float inv = 1.0f/(ar*ar + ai*ai);
    float wr = (zr*ar + zi*ai)*inv;
    float wi = (zi*ar - zr*ai)*inv;
    float br = Bre[i], bi = Bim[i];
    dAr[i]=dar; dAi[i]=dai;
    dBr[i]=wr*br - wi*bi;
    dBi[i]=wr*bi + wi*br;
}

// ---------------- in_proj ----------------
__global__ void k_inproj_x(const float* __restrict__ in, const float* __restrict__ w,
                           const float* __restrict__ bias, float* __restrict__ x){
    int i = blockIdx.x*256+threadIdx.x;          // b*T*H + t*H + h
    int h = i & (H-1);
    int bt = i >> 10;
    x[i] = in[bt]*w[h] + bias[h];
}
__global__ void k_inproj_xT(const float* __restrict__ in, const float* __restrict__ w,
                            const float* __restrict__ bias, float* __restrict__ xT){
    int i = blockIdx.x*256+threadIdx.x;          // b*H*T + h*T + t
    int t = i & (TLEN-1);
    int bh = i >> 9;
    int h = bh & (H-1);
    int b = bh >> 10;
    xT[i] = in[b*TLEN + t]*w[h] + bias[h];
}

// ---------------- S4 conv kernel gen ----------------
__global__ __launch_bounds__(64) void k_genK(
        const float* __restrict__ dAr, const float* __restrict__ dAi,
        const float* __restrict__ dBr, const float* __restrict__ dBi,
        const float* __restrict__ Cre, const float* __restrict__ Cim,
        float* __restrict__ Kbuf){
    __shared__ float trans[16][65];
    int lh = blockIdx.x;
    int lane = threadIdx.x;
    int pi = lh*NST + lane;
    float ar=dAr[pi], ai=dAi[pi];
    float br=dBr[pi], bi=dBi[pi];
    float cr=2.f*Cre[pi], ci=2.f*Cim[pi];
    float wr = cr*br - ci*bi;
    float wi = cr*bi + ci*br;
    float* Krow = Kbuf + (size_t)lh*TLEN;
    int r = lane>>2, q = lane&3;
    for (int c=0;c<TLEN/16;c++){
        #pragma unroll
        for (int i=0;i<16;i++){
            trans[i][lane] = wr;
            float nr = fmaf(wr,ar, -wi*ai);
            float ni = fmaf(wr,ai,  wi*ar);
            wr=nr; wi=ni;
        }
        __syncthreads();
        float s = 0.f;
        #pragma unroll
        for (int m=0;m<16;m++) s += trans[r][q*16+m];
        s += __shfl_xor(s,1,64);
        s += __shfl_xor(s,2,64);
        if (q==0) Krow[c*16 + r] = s;
        __syncthreads();
    }
}

// ---------------- causal Toeplitz conv + D*u + gelu; bf16 (B,H,T) out ----------------
#define CTT 256
#define CJT 64
__global__ __launch_bounds__(256) void k_conv(
        const float* __restrict__ u,            // (B,H,T) f32
        const float* __restrict__ Kbuf,         // (L,H,T)
        const float* __restrict__ Dv,
        __hip_bfloat16* __restrict__ g,         // (B,H,T) bf16
        int layer){
    __shared__ float u_s[CJT][33];
    __shared__ float Ks[CTT+CJT];
    int h  = blockIdx.y;
    int t0 = blockIdx.x * CTT;
    int tid = threadIdx.x;
    int bg = tid & 7;
    int tg = tid >> 3;
    const float* Krow = Kbuf + ((size_t)layer*H + h)*TLEN;
    float acc[8][4];
    #pragma unroll
    for (int i=0;i<8;i++){
        #pragma unroll
        for (int b=0;b<4;b++) acc[i][b]=0.f;
    }
    int ntile = t0/CJT + CTT/CJT;
    for (int jt=0; jt<ntile; jt++){
        int j0 = jt*CJT;
        __syncthreads();
        for (int i=tid; i<CTT+CJT; i+=256){
            int d = t0 - j0 - (CJT-1) + i;
            Ks[i] = (d>=0) ? Krow[d] : 0.f;
        }
        {
            int jj = tid & 63, bq = tid >> 6;
            #pragma unroll
            for (int p=0;p<8;p++){
                int b = bq + p*4;
                u_s[jj][b] = u[((size_t)b*H + h)*TLEN + j0 + jj];
            }
        }
        __syncthreads();
        #pragma unroll 8
        for (int j=0;j<CJT;j++){
            float4 ub = *(const float4*)&u_s[j][bg*4];
            int base = tg*8 + (CJT-1) - j;
            float kv[8];
            #pragma unroll
            for (int i=0;i<8;i++) kv[i] = Ks[base+i];
            #pragma unroll
            for (int i=0;i<8;i++){
                acc[i][0] = fmaf(kv[i], ub.x, acc[i][0]);
                acc[i][1] = fmaf(kv[i], ub.y, acc[i][1]);
                acc[i][2] = fmaf(kv[i], ub.z, acc[i][2]);
                acc[i][3] = fmaf(kv[i], ub.w, acc[i][3]);
            }
        }
    }
    float dv = Dv[layer*H + h];
    int tb = t0 + tg*8;
    #pragma unroll
    for (int b=0;b<4;b++){
        int bb = bg*4 + b;
        const float* urow = u + ((size_t)bb*H + h)*TLEN + tb;
        float4 u0 = *(const float4*)urow;
        float4 u1 = *(const float4*)(urow+4);
        bf16x8 o;
        o[0] = bfbits(gelu_f(fmaf(dv,u0.x, acc[0][b])));
        o[1] = bfbits(gelu_f(fmaf(dv,u0.y, acc[1][b])));
        o[2] = bfbits(gelu_f(fmaf(dv,u0.z, acc[2][b])));
        o[3] = bfbits(gelu_f(fmaf(dv,u0.w, acc[3][b])));
        o[4] = bfbits(gelu_f(fmaf(dv,u1.x, acc[4][b])));
        o[5] = bfbits(gelu_f(fmaf(dv,u1.y, acc[5][b])));
        o[6] = bfbits(gelu_f(fmaf(dv,u1.z, acc[6][b])));
        o[7] = bfbits(gelu_f(fmaf(dv,u1.w, acc[7][b])));
        *(bf16x8*)(g + ((size_t)bb*H + h)*TLEN + tb) = o;
    }
}

// ---------------- bf16 transpose (B,H,T) -> (B,T,H) ----------------
__global__ __launch_bounds__(256) void k_trcast_bf(const __hip_bfloat16* __restrict__ x,
                                                   __hip_bfloat16* __restrict__ y){
    __shared__ __hip_bfloat16 tile[32][34];
    int t0 = blockIdx.x*32, h0 = blockIdx.y*32, b = blockIdx.z;
    int tx = threadIdx.x & 31, ty = threadIdx.x >> 5;
    #pragma unroll
    for (int i=0;i<32;i+=8)
        tile[ty+i][tx] = x[((size_t)(b*H + h0+ty+i))*TLEN + t0+tx];
    __syncthreads();
    #pragma unroll
    for (int i=0;i<32;i+=8)
        y[((size_t)(b*TLEN + t0+ty+i))*H + h0+tx] = tile[tx][ty+i];
}

// ---------------- W (L,H,2H) f32 -> Wt (L,2H,H) bf16 (encoder GEMM B operand) ----------------
__global__ __launch_bounds__(256) void k_wtr(const float* __restrict__ W,
                                             __hip_bfloat16* __restrict__ Wt){
    __shared__ float tile[32][33];
    int n0 = blockIdx.x*32, k0 = blockIdx.y*32, l = blockIdx.z;
    const float* Wl = W + (size_t)l*H*H2;
    __hip_bfloat16* Wtl = Wt + (size_t)l*H*H2;
    int tx = threadIdx.x & 31, ty = threadIdx.x >> 5;
    #pragma unroll
    for (int i=0;i<32;i+=8)
        tile[ty+i][tx] = Wl[(size_t)(k0+ty+i)*H2 + n0+tx];
    __syncthreads();
    #pragma unroll
    for (int i=0;i<32;i+=8)
        Wtl[(size_t)(n0+ty+i)*H + k0+tx] = __float2bfloat16(tile[tx][ty+i]);
}

// ---------------- W (L,H,2H) f32 -> Wdt (L,2H,H) f32 (decode GEMM rows) ----------------
__global__ __launch_bounds__(256) void k_wtrf(const float* __restrict__ W,
                                              float* __restrict__ Wdt){
    __shared__ float tile[32][33];
    int n0 = blockIdx.x*32, k0 = blockIdx.y*32, l = blockIdx.z;
    const float* Wl = W + (size_t)l*H*H2;
    float* Wo = Wdt + (size_t)l*H2*H;
    int tx = threadIdx.x & 31, ty = threadIdx.x >> 5;
    #pragma unroll
    for (int i=0;i<32;i+=8)
        tile[ty+i][tx] = Wl[(size_t)(k0+ty+i)*H2 + n0+tx];
    __syncthreads();
    #pragma unroll
    for (int i=0;i<32;i+=8)
        Wo[(size_t)(n0+ty+i)*H + k0+tx] = tile[tx][ty+i];
}

// ---------------- bf16 MFMA GEMM + bias + GLU fused (encoder) ----------------
__global__ __launch_bounds__(256) void k_gemm_glu_mfma(
        const __hip_bfloat16* __restrict__ Abf,
        const __hip_bfloat16* __restrict__ Wt,
        const float* __restrict__ bias2,         // (2048,)
        float* __restrict__ glu){                // (M,1024)
    __shared__ alignas(16) short As[128*32];
    __shared__ alignas(16) short Bs[128*32];
    const int K = 1024;
    int tid = threadIdx.x;
    int lane = tid & 63, wid = tid >> 6;
    int m0 = blockIdx.x * 128;
    int nb = blockIdx.y * 64;
    int g0 = tid, g1 = tid + 256;
    int r0 = g0 >> 2, r1 = g1 >> 2;
    int wtr0 = nb + ((r0>>6)<<5) + (r0&31) + ((r0>>5)&1)*1024;
    int wtr1 = nb + ((r1>>6)<<5) + (r1&31) + ((r1>>5)&1)*1024;
    const short* Ap = (const short*)Abf;
    const short* Bp = (const short*)Wt;
    const short* Ag0 = Ap + (size_t)(m0 + r0)*K + (g0&3)*8;
    const short* Ag1 = Ap + (size_t)(m0 + r1)*K + (g1&3)*8;
    const short* Bg0 = Bp + (size_t)wtr0*K + (g0&3)*8;
    const short* Bg1 = Bp + (size_t)wtr1*K + (g1&3)*8;
    char* AsB = (char*)As;
    char* BsB = (char*)Bs;
    int wr = wid >> 1, wc = wid & 1;
    int mo = wr*64, no = wc*64;
    f32x4 acc[4][4] = {};
    int arow = (lane & 15)*32 + (lane>>4)*8;
    for (int k0 = 0; k0 < K; k0 += 32){
        gload16(Ag0 + k0, AsB + wid*1024);
        gload16(Ag1 + k0, AsB + 4096 + wid*1024);
        gload16(Bg0 + k0, BsB + wid*1024);
        gload16(Bg1 + k0, BsB + 4096 + wid*1024);
        asm volatile("s_waitcnt vmcnt(0)" ::: "memory");
        __syncthreads();
        bf16x8 a[4], b[4];
        #pragma unroll
        for (int mi=0;mi<4;mi++)
            a[mi] = *(const bf16x8*)(As + (mo + mi*16)*32 + arow);
        #pragma unroll
        for (int ni=0;ni<4;ni++)
            b[ni] = *(const bf16x8*)(Bs + (no + ni*16)*32 + arow);
        #pragma unroll
        for (int mi=0;mi<4;mi++){
            #pragma unroll
            for (int ni=0;ni<4;ni++){
                acc[mi][ni] = __builtin_amdgcn_mfma_f32_16x16x32_bf16(a[mi], b[ni], acc[mi][ni], 0, 0, 0);
            }
        }
        __syncthreads();
    }
    int cbase = nb + wc*32 + (lane&15);
    #pragma unroll
    for (int ni=0;ni<2;ni++){
        int c = cbase + ni*16;
        float ba = bias2[c], bb = bias2[c+1024];
        #pragma unroll
        for (int mi=0;mi<4;mi++){
            #pragma unroll
            for (int r=0;r<4;r++){
                size_t m = m0 + mo + mi*16 + (lane>>4)*4 + r;
                float za = acc[mi][ni][r] + ba;
                float zb = acc[mi][ni+2][r] + bb;
                glu[m*H + c] = za * sigm_f(zb);
            }
        }
    }
}

// ---------------- LayerNorm over H per (b,t) row (encoder) ----------------
__global__ __launch_bounds__(256) void k_ln(const float* __restrict__ glu, const float* __restrict__ res,
        const float* __restrict__ gamma, const float* __restrict__ beta, float* __restrict__ outx){
    __shared__ float red[8];
    int row = blockIdx.x;
    int tid = threadIdx.x;
    float4 gv = *(const float4*)(glu + (size_t)row*H + tid*4);
    float4 rv = *(const float4*)(res + (size_t)row*H + tid*4);
    float x0=gv.x+rv.x, x1=gv.y+rv.y, x2=gv.z+rv.z, x3=gv.w+rv.w;
    float s = x0+x1+x2+x3;
    float q = x0*x0+x1*x1+x2*x2+x3*x3;
    #pragma unroll
    for (int m=32;m>=1;m>>=1){ s += __shfl_xor(s,m,64); q += __shfl_xor(q,m,64); }
    int wv = tid>>6;
    if ((tid&63)==0){ red[wv]=s; red[4+wv]=q; }
    __syncthreads();
    s = red[0]+red[1]+red[2]+red[3];
    q = red[4]+red[5]+red[6]+red[7];
    float m = s*(1.0f/H);
    float v = q*(1.0f/H) - m*m;
    float rstd = rsqrtf(v + 1e-5f);
    float4 gm = *(const float4*)(gamma + tid*4);
    float4 bt = *(const float4*)(beta + tid*4);
    float4 o;
    o.x = (x0-m)*rstd*gm.x + bt.x;
    o.y = (x1-m)*rstd*gm.y + bt.y;
    o.z = (x2-m)*rstd*gm.z + bt.z;
    o.w = (x3-m)*rstd*gm.w + bt.w;
    *(float4*)(outx + (size_t)row*H + tid*4) = o;
}

// ---------------- transpose (b,t,h) -> (b,h,t) f32 ----------------
__global__ __launch_bounds__(256) void k_transpose(const float* __restrict__ x, float* __restrict__ xT){
    __shared__ float tile[32][33];
    int t0 = blockIdx.x*32, h0 = blockIdx.y*32, b = blockIdx.z;
    int tx = threadIdx.x & 31, ty = threadIdx.x >> 5;
    #pragma unroll
    for (int i=0;i<32;i+=8)
        tile[ty+i][tx] = x[((size_t)(b*TLEN + t0+ty+i))*H + h0+tx];
    __syncthreads();
    #pragma unroll
    for (int i=0;i<32;i+=8)
        xT[((size_t)(b*H + h0+ty+i))*TLEN + t0+tx] = tile[tx][ty+i];
}

__global__ void k_ctx(const float* __restrict__ x, float* __restrict__ ctx){
    int i = blockIdx.x*256+threadIdx.x;
    int b = i>>10, h = i&(H-1);
    ctx[i] = x[((size_t)(b*TLEN + TLEN-1))*H + h];
}

// ======================= PERSISTENT DECODE =======================
// 256 blocks x 256 threads, regular launch (graph-capture safe).
// Generation barrier: flag-per-block (128B stride, no contention), block-0
// gathers with 256 parallel threads, single release word. g = 1..96.
#define FLAGSTRIDE 32
__device__ __forceinline__ void gbar(int* flags, int* rel, int g, int blk, int tid){
    __syncthreads();
    if (blk == 0){
        if (tid > 0){
            int it = 0;
            while (__hip_atomic_load(&flags[tid*FLAGSTRIDE], __ATOMIC_RELAXED,
                                     __HIP_MEMORY_SCOPE_AGENT) < g){
                __builtin_amdgcn_s_sleep(1);
                if (++it > 1000000) break;   // escape: broken barrier -> wrong answer, not hang
            }
        }
        __syncthreads();
        if (tid == 0){
            __threadfence();
            __hip_atomic_store(rel, g, __ATOMIC_RELEASE, __HIP_MEMORY_SCOPE_AGENT);
        }
        __syncthreads();
    } else {
        if (tid == 0){
            __threadfence();
            __hip_atomic_store(&flags[blk*FLAGSTRIDE], g, __ATOMIC_RELEASE,
                               __HIP_MEMORY_SCOPE_AGENT);
            int it = 0;
            while (__hip_atomic_load(rel, __ATOMIC_RELAXED, __HIP_MEMORY_SCOPE_AGENT) < g){
                __builtin_amdgcn_s_sleep(1);
                if (++it > 1000000) break;
            }
            __threadfence();
        }
        __syncthreads();
    }
}

// decode GEMM phase: blocks 0..127, p = blk*8 + (tid>>5) in [0,1024), b = tid&31.
__device__ __forceinline__ void dec_gemm_p(int blk, int tid, float (*u_s)[260],
        const float* __restrict__ ygel, const float* __restrict__ Wdt,
        const float* __restrict__ b2, float* __restrict__ glud){
    int p = blk*8 + (tid>>5);
    int b = tid & 31;
    const float* wa = Wdt + (size_t)p*H;
    const float* wb = Wdt + (size_t)(p+1024)*H;
    float aa=0.f, ab=0.f;
    int row = tid & 31, cc = (tid>>5)*4;
    for (int kq=0; kq<4; kq++){
        __syncthreads();
        #pragma unroll
        for (int i=0;i<8;i++){
            int col = cc + i*32;
            *(float4*)&u_s[row][col] = *(const float4*)&ygel[row*H + kq*256 + col];
        }
        __syncthreads();
        const float* wak = wa + kq*256;
        const float* wbk = wb + kq*256;
        #pragma unroll 8
        for (int k=0;k<256;k+=8){
            float4 u0 = *(const float4*)&u_s[b][k];
            float4 u1 = *(const float4*)&u_s[b][k+4];
            float4 wa0 = *(const float4*)(wak + k);
            float4 wa1 = *(const float4*)(wak + k + 4);
            float4 wb0 = *(const float4*)(wbk + k);
            float4 wb1 = *(const float4*)(wbk + k + 4);
            aa = fmaf(u0.x,wa0.x, fmaf(u0.y,wa0.y, fmaf(u0.z,wa0.z, fmaf(u0.w,wa0.w, aa))));
            aa = fmaf(u1.x,wa1.x, fmaf(u1.y,wa1.y, fmaf(u1.z,wa1.z, fmaf(u1.w,wa1.w, aa))));
            ab = fmaf(u0.x,wb0.x, fmaf(u0.y,wb0.y, fmaf(u0.z,wb0.z, fmaf(u0.w,wb0.w, ab))));
            ab = fmaf(u1.x,wb1.x, fmaf(u1.y,wb1.y, fmaf(u1.z,wb1.z, fmaf(u1.w,wb1.w, ab))));
        }
    }
    glud[b*H + p] = (aa + b2[p]) * sigm_f(ab + b2[p+H]);
}

__device__ __forceinline__ void dec_ln_phase(int b, int tid, float* red,
        const float* __restrict__ glud, const float* __restrict__ gamma,
        const float* __restrict__ beta, float* __restrict__ decout,
        const float* __restrict__ ctx, const float* __restrict__ headw,
        const float* __restrict__ headb, float* __restrict__ bits,
        float* __restrict__ out, int step, int last){
    float4 gv = *(const float4*)(glud + (size_t)b*H + tid*4);
    float x0,x1,x2,x3;
    if (step==0){ x0=gv.x; x1=gv.y; x2=gv.z; x3=gv.w; }           // res = u0 = 0
    else        { x0=2.f*gv.x; x1=2.f*gv.y; x2=2.f*gv.z; x3=2.f*gv.w; }  // res = y
    float s = x0+x1+x2+x3, q = x0*x0+x1*x1+x2*x2+x3*x3;
    #pragma unroll
    for (int m=32;m>=1;m>>=1){ s+=__shfl_xor(s,m,64); q+=__shfl_xor(q,m,64); }
    int wv = tid>>6;
    if ((tid&63)==0){ red[wv]=s; red[4+wv]=q; }
    __syncthreads();
    s = red[0]+red[1]+red[2]+red[3];
    q = red[4]+red[5]+red[6]+red[7];
    float m = s*(1.f/H), v = q*(1.f/H)-m*m, rstd = rsqrtf(v+1e-5f);
    float4 gm = *(const float4*)(gamma + tid*4);
    float4 bt = *(const float4*)(beta + tid*4);
    float d0 = (x0-m)*rstd*gm.x+bt.x;
    float d1 = (x1-m)*rstd*gm.y+bt.y;
    float d2 = (x2-m)*rstd*gm.z+bt.z;
    float d3 = (x3-m)*rstd*gm.w+bt.w;
    if (!last){
        float4 o; o.x=d0;o.y=d1;o.z=d2;o.w=d3;
        *(float4*)(decout + (size_t)b*H + tid*4) = o;
    } else {
        float4 cv = *(const float4*)(ctx + (size_t)b*H + tid*4);
        d0+=cv.x; d1+=cv.y; d2+=cv.z; d3+=cv.w;
        float4 hw = *(const float4*)(headw + tid*4);
        float hp = d0*hw.x + d1*hw.y + d2*hw.z + d3*hw.w;
        #pragma unroll
        for (int mm=32;mm>=1;mm>>=1) hp += __shfl_xor(hp,mm,64);
        __syncthreads();
        if ((tid&63)==0) red[wv]=hp;
        __syncthreads();
        if (tid==0){
            float hs = red[0]+red[1]+red[2]+red[3] + headb[0];
            float bit = sigm_f(hs);
            bits[b] = bit;
            out[b*NSTEPS + step] = bit;
        }
    }
}

__global__ __launch_bounds__(256, 1) void k_decode(
        const float* __restrict__ dAr, const float* __restrict__ dAi,
        const float* __restrict__ dBr, const float* __restrict__ dBi,
        const float* __restrict__ Cre, const float* __restrict__ Cim,
        const float* __restrict__ Dv,
        const float* __restrict__ Wdt, const float* __restrict__ bias2,
        const float* __restrict__ lng, const float* __restrict__ lnb,
        const float* __restrict__ ctx, const float* __restrict__ headw,
        const float* __restrict__ headb,
        float* __restrict__ ygel, float* __restrict__ glud,
        float* __restrict__ dec, float* __restrict__ bits,
        float* __restrict__ out, int* __restrict__ barmem){
    __shared__ float u_s[32][260];
    __shared__ float red[8];
    int blk = blockIdx.x, tid = threadIdx.x;
    int* flags = barmem;
    int* rel   = barmem + DECBLK*FLAGSTRIDE;
    int gtid = blk*256 + tid;
    int pair = gtid >> 1, half = gtid & 1;   // pair = b*H + h
    int pb = pair >> 10, ph = pair & 1023;
    float s0r[32], s0i[32], s1r[32], s1i[32];
    #pragma unroll
    for (int j=0;j<32;j++){ s0r[j]=0.f; s0i[j]=0.f; s1r[j]=0.f; s1i[j]=0.f; }
    int g = 1;
    for (int step=0; step<NSTEPS; step++){
        // ---- layer 0 state: thread owns 32 states of (pair, half)
        {
            float u = (step==0) ? 0.f : bits[pb];
            int p0 = ph*NST + half*32;
            float c = 0.f;
            #pragma unroll
            for (int j=0;j<32;j++){
                float ar=dAr[p0+j], ai=dAi[p0+j], br=dBr[p0+j], bj=dBi[p0+j];
                float nr = fmaf(ar,s0r[j], fmaf(-ai,s0i[j], br*u));
                float ni = fmaf(ai,s0r[j], fmaf( ar,s0i[j], bj*u));
                s0r[j]=nr; s0i[j]=ni;
                c = fmaf(Cre[p0+j], nr, fmaf(-Cim[p0+j], ni, c));
            }
            c += __shfl_xor(c, 1, 64);
            if (!half) ygel[pair] = gelu_f(2.f*c + Dv[ph]*u);
        }
        gbar(flags, rel, g++, blk, tid);
        if (blk < 128) dec_gemm_p(blk, tid, u_s, ygel, Wdt, bias2, glud);
        gbar(flags, rel, g++, blk, tid);
        if (blk < 32) dec_ln_phase(blk, tid, red, glud, lng, lnb, dec,
                                   ctx, headw, headb, bits, out, step, 0);
        gbar(flags, rel, g++, blk, tid);
        // ---- layer 1 state (u = dec)
        {
            float u = dec[pair];
            int p1 = (H + ph)*NST + half*32;
            float c = 0.f;
            #pragma unroll
            for (int j=0;j<32;j++){
                float ar=dAr[p1+j], ai=dAi[p1+j], br=dBr[p1+j], bj=dBi[p1+j];
                float nr = fmaf(ar,s1r[j], fmaf(-ai,s1i[j], br*u));
                float ni = fmaf(ai,s1r[j], fmaf( ar,s1i[j], bj*u));
                s1r[j]=nr; s1i[j]=ni;
                c = fmaf(Cre[p1+j], nr, fmaf(-Cim[p1+j], ni, c));
            }
            c += __shfl_xor(c, 1, 64);
            if (!half) ygel[pair] = gelu_f(2.f*c + Dv[H+ph]*u);
        }
        gbar(flags, rel, g++, blk, tid);
        if (blk < 128) dec_gemm_p(blk, tid, u_s, ygel, Wdt + (size_t)H2*H, bias2 + H2, glud);
        gbar(flags, rel, g++, blk, tid);
        if (blk < 32) dec_ln_phase(blk, tid, red, glud, lng+H, lnb+H, dec,
                                   ctx, headw, headb, bits, out, step, 1);
        gbar(flags, rel, g++, blk, tid);
    }
}

extern "C" void kernel_launch(void* const* d_in, const int* in_sizes, int n_in,
                              void* d_out, int out_size, void* d_ws, size_t ws_size,
                              hipStream_t stream) {
    const float* in_seq = (const float*)d_in[0];
    const float* inw  = (const float*)d_in[2];
    const float* inb  = (const float*)d_in[3];
    const float* log_dt = (const float*)d_in[4];
    const float* Are = (const float*)d_in[5];
    const float* Aim = (const float*)d_in[6];
    const float* Bre = (const float*)d_in[7];
    const float* Bim = (const float*)d_in[8];
    const float* Cre = (const float*)d_in[9];
    const float* Cim = (const float*)d_in[10];
    const float* Dv  = (const float*)d_in[11];
    const float* outw = (const float*)d_in[12];
    const float* outb = (const float*)d_in[13];
    const float* lng = (const float*)d_in[14];
    const float* lnb = (const float*)d_in[15];
    const float* headw = (const float*)d_in[16];
    const float* headb = (const float*)d_in[17];
    float* out = (float*)d_out;

    float* ws = (float*)d_ws;
    size_t off = 0;
    auto alloc = [&](size_t n){ float* p = ws + off; off += n; return p; };
    float* dAr = alloc((size_t)LAYN*H*NST);
    float* dAi = alloc((size_t)LAYN*H*NST);
    float* dBr = alloc((size_t)LAYN*H*NST);
    float* dBi = alloc((size_t)LAYN*H*NST);
    float* Kbuf = alloc((size_t)LAYN*H*TLEN);
    float* bufA = alloc((size_t)BSZ*TLEN*H);                              // 67MB
    float* bufB = alloc((size_t)BSZ*TLEN*H);                              // 67MB
    __hip_bfloat16* gbf = (__hip_bfloat16*)alloc((size_t)BSZ*TLEN*H/2);   // 33.5MB
    float* ctx = alloc((size_t)BSZ*H);
    float* sre = alloc((size_t)LAYN*BSZ*H*NST);                           // 16.8MB
    float* sim = alloc((size_t)LAYN*BSZ*H*NST);                           // 16.8MB
    __hip_bfloat16* Abf = (__hip_bfloat16*)sre;  // alias: Abf dead before decode
    __hip_bfloat16* Wt  = (__hip_bfloat16*)alloc((size_t)LAYN*H*H2/2);    // 8.4MB
    float* Wdt = alloc((size_t)LAYN*H2*H);                                // 16.8MB
    float* ygel = alloc((size_t)BSZ*H);
    float* glud = alloc((size_t)BSZ*H);
    float* dec  = alloc((size_t)BSZ*H);
    float* bits = alloc(64);
    int*   bar  = (int*)alloc(DECBLK*FLAGSTRIDE + 64);
    // total ~233 MB (round-3's proven 241.7 MB OK; round-4's 283.6 MB crashed)

    k_precompute<<<(LAYN*H*NST+255)/256, 256, 0, stream>>>(log_dt,Are,Aim,Bre,Bim,dAr,dAi,dBr,dBi);
    k_genK<<<LAYN*H, 64, 0, stream>>>(dAr,dAi,dBr,dBi,Cre,Cim,Kbuf);
    k_wtr<<<dim3(H2/32, H/32, LAYN), 256, 0, stream>>>(outw, Wt);
    k_wtrf<<<dim3(H2/32, H/32, LAYN), 256, 0, stream>>>(outw, Wdt);
    k_inproj_x <<<(BSZ*TLEN*H)/256, 256, 0, stream>>>(in_seq, inw, inb, bufA);
    k_inproj_xT<<<(BSZ*TLEN*H)/256, 256, 0, stream>>>(in_seq, inw, inb, bufB);

    // ---- layer 0: res = bufA (b,t,h); xT = bufB (b,h,t)
    k_conv<<<dim3(TLEN/CTT, H), 256, 0, stream>>>(bufB, Kbuf, Dv, gbf, 0);
    k_trcast_bf<<<dim3(TLEN/32, H/32, BSZ), 256, 0, stream>>>(gbf, Abf);
    k_gemm_glu_mfma<<<dim3(BSZ*TLEN/128, H/64), 256, 0, stream>>>(Abf, Wt, outb, bufB);
    k_ln<<<BSZ*TLEN, 256, 0, stream>>>(bufB, bufA, lng, lnb, bufA);
    k_transpose<<<dim3(16,32,32), 256, 0, stream>>>(bufA, bufB);

    // ---- layer 1
    k_conv<<<dim3(TLEN/CTT, H), 256, 0, stream>>>(bufB, Kbuf, Dv, gbf, 1);
    k_trcast_bf<<<dim3(TLEN/32, H/32, BSZ), 256, 0, stream>>>(gbf, Abf);
    k_gemm_glu_mfma<<<dim3(BSZ*TLEN/128, H/64), 256, 0, stream>>>(Abf, Wt + (size_t)H*H2, outb + H2, bufB);
    k_ln<<<BSZ*TLEN, 256, 0, stream>>>(bufB, bufA, lng+H, lnb+H, bufA);

    k_ctx<<<(BSZ*H)/256, 256, 0, stream>>>(bufA, ctx);

    // ---- decode: one persistent kernel, 96 generation barriers
    hipMemsetAsync(bar, 0, sizeof(int)*(DECBLK*FLAGSTRIDE + 64), stream);
    k_decode<<<DECBLK, 256, 0, stream>>>(dAr,dAi,dBr,dBi,Cre,Cim,Dv,
                                         Wdt, outb, lng, lnb, ctx, headw, headb,
                                         ygel, glud, dec, bits, out, bar);
}

// Round 9
// 2426.450 us; speedup vs baseline: 1.6547x; 1.3745x over previous
//
#include <hip/hip_runtime.h>
#include <hip/hip_bf16.h>
#include <math.h>

#define H    1024
#define NST  64
#define LAYN 2
#define BSZ  32
#define TLEN 512
#define NSTEPS 16
#define H2   2048
#define DECBLK 256

typedef __attribute__((ext_vector_type(8))) short bf16x8;
typedef __attribute__((ext_vector_type(4))) float f32x4;

__device__ __forceinline__ float gelu_f(float x){
    return 0.5f*x*(1.0f+erff(x*0.7071067811865475f));
}
__device__ __forceinline__ float sigm_f(float x){
    return 1.0f/(1.0f+expf(-x));
}
__device__ __forceinline__ short bfbits(float x){
    __hip_bfloat16 h = __float2bfloat16(x);
    return *(short*)&h;
}
__device__ __forceinline__ void gload16(const void* g, void* l){
    __builtin_amdgcn_global_load_lds((const __attribute__((address_space(1))) void*)g,
                                     (__attribute__((address_space(3))) void*)l, 16, 0, 0);
}

// ---------------- discretized SSM params ----------------
__global__ void k_precompute(const float* __restrict__ log_dt,
                             const float* __restrict__ Are, const float* __restrict__ Aim,
                             const float* __restrict__ Bre, const float* __restrict__ Bim,
                             float* __restrict__ dAr, float* __restrict__ dAi,
                             float* __restrict__ dBr, float* __restrict__ dBi){
    int i = blockIdx.x*256 + threadIdx.x;
    if (i >= LAYN*H*NST) return;
    int lh = i / NST;
    float dt = expf(log_dt[lh]);
    float ar = Are[i], ai = Aim[i];
    float e  = expf(dt*ar);
    float sa, ca; sincosf(dt*ai, &sa, &ca);
    float dar = e*ca, dai = e*sa;
    float zr = dar-1.0f, zi = dai;
    float inv = 1.0f/(ar*ar + ai*ai);
    float wr = (zr*ar + zi*ai)*inv;
    float wi = (zi*ar - zr*ai)*inv;
    float br = Bre[i], bi = Bim[i];
    dAr[i]=dar; dAi[i]=dai;
    dBr[i]=wr*br - wi*bi;
    dBi[i]=wr*bi + wi*br;
}

// ---------------- in_proj ----------------
__global__ void k_inproj_x(const float* __restrict__ in, const float* __restrict__ w,
                           const float* __restrict__ bias, float* __restrict__ x){
    int i = blockIdx.x*256+threadIdx.x;          // b*T*H + t*H + h
    int h = i & (H-1);
    int bt = i >> 10;
    x[i] = in[bt]*w[h] + bias[h];
}
__global__ void k_inproj_xT(const float* __restrict__ in, const float* __restrict__ w,
                            const float* __restrict__ bias, float* __restrict__ xT){
    int i = blockIdx.x*256+threadIdx.x;          // b*H*T + h*T + t
    int t = i & (TLEN-1);
    int bh = i >> 9;
    int h = bh & (H-1);
    int b = bh >> 10;
    xT[i] = in[b*TLEN + t]*w[h] + bias[h];
}

// ---------------- S4 conv kernel gen ----------------
__global__ __launch_bounds__(64) void k_genK(
        const float* __restrict__ dAr, const float* __restrict__ dAi,
        const float* __restrict__ dBr, const float* __restrict__ dBi,
        const float* __restrict__ Cre, const float* __restrict__ Cim,
        float* __restrict__ Kbuf){
    __shared__ float trans[16][65];
    int lh = blockIdx.x;
    int lane = threadIdx.x;
    int pi = lh*NST + lane;
    float ar=dAr[pi], ai=dAi[pi];
    float br=dBr[pi], bi=dBi[pi];
    float cr=2.f*Cre[pi], ci=2.f*Cim[pi];
    float wr = cr*br - ci*bi;
    float wi = cr*bi + ci*br;
    float* Krow = Kbuf + (size_t)lh*TLEN;
    int r = lane>>2, q = lane&3;
    for (int c=0;c<TLEN/16;c++){
        #pragma unroll
        for (int i=0;i<16;i++){
            trans[i][lane] = wr;
            float nr = fmaf(wr,ar, -wi*ai);
            float ni = fmaf(wr,ai,  wi*ar);
            wr=nr; wi=ni;
        }
        __syncthreads();
        float s = 0.f;
        #pragma unroll
        for (int m=0;m<16;m++) s += trans[r][q*16+m];
        s += __shfl_xor(s,1,64);
        s += __shfl_xor(s,2,64);
        if (q==0) Krow[c*16 + r] = s;
        __syncthreads();
    }
}

// ---------------- causal Toeplitz conv + D*u + gelu; bf16 (B,H,T) out ----------------
#define CTT 256
#define CJT 64
__global__ __launch_bounds__(256) void k_conv(
        const float* __restrict__ u,            // (B,H,T) f32
        const float* __restrict__ Kbuf,         // (L,H,T)
        const float* __restrict__ Dv,
        __hip_bfloat16* __restrict__ g,         // (B,H,T) bf16
        int layer){
    __shared__ float u_s[CJT][33];
    __shared__ float Ks[CTT+CJT];
    int h  = blockIdx.y;
    int t0 = blockIdx.x * CTT;
    int tid = threadIdx.x;
    int bg = tid & 7;
    int tg = tid >> 3;
    const float* Krow = Kbuf + ((size_t)layer*H + h)*TLEN;
    float acc[8][4];
    #pragma unroll
    for (int i=0;i<8;i++){
        #pragma unroll
        for (int b=0;b<4;b++) acc[i][b]=0.f;
    }
    int ntile = t0/CJT + CTT/CJT;
    for (int jt=0; jt<ntile; jt++){
        int j0 = jt*CJT;
        __syncthreads();
        for (int i=tid; i<CTT+CJT; i+=256){
            int d = t0 - j0 - (CJT-1) + i;
            Ks[i] = (d>=0) ? Krow[d] : 0.f;
        }
        {
            int jj = tid & 63, bq = tid >> 6;
            #pragma unroll
            for (int p=0;p<8;p++){
                int b = bq + p*4;
                u_s[jj][b] = u[((size_t)b*H + h)*TLEN + j0 + jj];
            }
        }
        __syncthreads();
        #pragma unroll 8
        for (int j=0;j<CJT;j++){
            float4 ub = *(const float4*)&u_s[j][bg*4];
            int base = tg*8 + (CJT-1) - j;
            float kv[8];
            #pragma unroll
            for (int i=0;i<8;i++) kv[i] = Ks[base+i];
            #pragma unroll
            for (int i=0;i<8;i++){
                acc[i][0] = fmaf(kv[i], ub.x, acc[i][0]);
                acc[i][1] = fmaf(kv[i], ub.y, acc[i][1]);
                acc[i][2] = fmaf(kv[i], ub.z, acc[i][2]);
                acc[i][3] = fmaf(kv[i], ub.w, acc[i][3]);
            }
        }
    }
    float dv = Dv[layer*H + h];
    int tb = t0 + tg*8;
    #pragma unroll
    for (int b=0;b<4;b++){
        int bb = bg*4 + b;
        const float* urow = u + ((size_t)bb*H + h)*TLEN + tb;
        float4 u0 = *(const float4*)urow;
        float4 u1 = *(const float4*)(urow+4);
        bf16x8 o;
        o[0] = bfbits(gelu_f(fmaf(dv,u0.x, acc[0][b])));
        o[1] = bfbits(gelu_f(fmaf(dv,u0.y, acc[1][b])));
        o[2] = bfbits(gelu_f(fmaf(dv,u0.z, acc[2][b])));
        o[3] = bfbits(gelu_f(fmaf(dv,u0.w, acc[3][b])));
        o[4] = bfbits(gelu_f(fmaf(dv,u1.x, acc[4][b])));
        o[5] = bfbits(gelu_f(fmaf(dv,u1.y, acc[5][b])));
        o[6] = bfbits(gelu_f(fmaf(dv,u1.z, acc[6][b])));
        o[7] = bfbits(gelu_f(fmaf(dv,u1.w, acc[7][b])));
        *(bf16x8*)(g + ((size_t)bb*H + h)*TLEN + tb) = o;
    }
}

// ---------------- bf16 transpose (B,H,T) -> (B,T,H) ----------------
__global__ __launch_bounds__(256) void k_trcast_bf(const __hip_bfloat16* __restrict__ x,
                                                   __hip_bfloat16* __restrict__ y){
    __shared__ __hip_bfloat16 tile[32][34];
    int t0 = blockIdx.x*32, h0 = blockIdx.y*32, b = blockIdx.z;
    int tx = threadIdx.x & 31, ty = threadIdx.x >> 5;
    #pragma unroll
    for (int i=0;i<32;i+=8)
        tile[ty+i][tx] = x[((size_t)(b*H + h0+ty+i))*TLEN + t0+tx];
    __syncthreads();
    #pragma unroll
    for (int i=0;i<32;i+=8)
        y[((size_t)(b*TLEN + t0+ty+i))*H + h0+tx] = tile[tx][ty+i];
}

// ---------------- W (L,H,2H) f32 -> Wt (L,2H,H) bf16 (encoder GEMM B operand) ----------------
__global__ __launch_bounds__(256) void k_wtr(const float* __restrict__ W,
                                             __hip_bfloat16* __restrict__ Wt){
    __shared__ float tile[32][33];
    int n0 = blockIdx.x*32, k0 = blockIdx.y*32, l = blockIdx.z;
    const float* Wl = W + (size_t)l*H*H2;
    __hip_bfloat16* Wtl = Wt + (size_t)l*H*H2;
    int tx = threadIdx.x & 31, ty = threadIdx.x >> 5;
    #pragma unroll
    for (int i=0;i<32;i+=8)
        tile[ty+i][tx] = Wl[(size_t)(k0+ty+i)*H2 + n0+tx];
    __syncthreads();
    #pragma unroll
    for (int i=0;i<32;i+=8)
        Wtl[(size_t)(n0+ty+i)*H + k0+tx] = __float2bfloat16(tile[tx][ty+i]);
}

// ---------------- W (L,H,2H) f32 -> Wdt (L,2H,H) f32 (decode GEMM rows) ----------------
__global__ __launch_bounds__(256) void k_wtrf(const float* __restrict__ W,
                                              float* __restrict__ Wdt){
    __shared__ float tile[32][33];
    int n0 = blockIdx.x*32, k0 = blockIdx.y*32, l = blockIdx.z;
    const float* Wl = W + (size_t)l*H*H2;
    float* Wo = Wdt + (size_t)l*H2*H;
    int tx = threadIdx.x & 31, ty = threadIdx.x >> 5;
    #pragma unroll
    for (int i=0;i<32;i+=8)
        tile[ty+i][tx] = Wl[(size_t)(k0+ty+i)*H2 + n0+tx];
    __syncthreads();
    #pragma unroll
    for (int i=0;i<32;i+=8)
        Wo[(size_t)(n0+ty+i)*H + k0+tx] = tile[tx][ty+i];
}

// ---------------- bf16 MFMA GEMM + bias + GLU fused (encoder) ----------------
__global__ __launch_bounds__(256) void k_gemm_glu_mfma(
        const __hip_bfloat16* __restrict__ Abf,
        const __hip_bfloat16* __restrict__ Wt,
        const float* __restrict__ bias2,         // (2048,)
        float* __restrict__ glu){                // (M,1024)
    __shared__ alignas(16) short As[128*32];
    __shared__ alignas(16) short Bs[128*32];
    const int K = 1024;
    int tid = threadIdx.x;
    int lane = tid & 63, wid = tid >> 6;
    int m0 = blockIdx.x * 128;
    int nb = blockIdx.y * 64;
    int g0 = tid, g1 = tid + 256;
    int r0 = g0 >> 2, r1 = g1 >> 2;
    int wtr0 = nb + ((r0>>6)<<5) + (r0&31) + ((r0>>5)&1)*1024;
    int wtr1 = nb + ((r1>>6)<<5) + (r1&31) + ((r1>>5)&1)*1024;
    const short* Ap = (const short*)Abf;
    const short* Bp = (const short*)Wt;
    const short* Ag0 = Ap + (size_t)(m0 + r0)*K + (g0&3)*8;
    const short* Ag1 = Ap + (size_t)(m0 + r1)*K + (g1&3)*8;
    const short* Bg0 = Bp + (size_t)wtr0*K + (g0&3)*8;
    const short* Bg1 = Bp + (size_t)wtr1*K + (g1&3)*8;
    char* AsB = (char*)As;
    char* BsB = (char*)Bs;
    int wr = wid >> 1, wc = wid & 1;
    int mo = wr*64, no = wc*64;
    f32x4 acc[4][4] = {};
    int arow = (lane & 15)*32 + (lane>>4)*8;
    for (int k0 = 0; k0 < K; k0 += 32){
        gload16(Ag0 + k0, AsB + wid*1024);
        gload16(Ag1 + k0, AsB + 4096 + wid*1024);
        gload16(Bg0 + k0, BsB + wid*1024);
        gload16(Bg1 + k0, BsB + 4096 + wid*1024);
        asm volatile("s_waitcnt vmcnt(0)" ::: "memory");
        __syncthreads();
        bf16x8 a[4], b[4];
        #pragma unroll
        for (int mi=0;mi<4;mi++)
            a[mi] = *(const bf16x8*)(As + (mo + mi*16)*32 + arow);
        #pragma unroll
        for (int ni=0;ni<4;ni++)
            b[ni] = *(const bf16x8*)(Bs + (no + ni*16)*32 + arow);
        #pragma unroll
        for (int mi=0;mi<4;mi++){
            #pragma unroll
            for (int ni=0;ni<4;ni++){
                acc[mi][ni] = __builtin_amdgcn_mfma_f32_16x16x32_bf16(a[mi], b[ni], acc[mi][ni], 0, 0, 0);
            }
        }
        __syncthreads();
    }
    int cbase = nb + wc*32 + (lane&15);
    #pragma unroll
    for (int ni=0;ni<2;ni++){
        int c = cbase + ni*16;
        float ba = bias2[c], bb = bias2[c+1024];
        #pragma unroll
        for (int mi=0;mi<4;mi++){
            #pragma unroll
            for (int r=0;r<4;r++){
                size_t m = m0 + mo + mi*16 + (lane>>4)*4 + r;
                float za = acc[mi][ni][r] + ba;
                float zb = acc[mi][ni+2][r] + bb;
                glu[m*H + c] = za * sigm_f(zb);
            }
        }
    }
}

// ---------------- LayerNorm over H per (b,t) row (encoder) ----------------
__global__ __launch_bounds__(256) void k_ln(const float* __restrict__ glu, const float* __restrict__ res,
        const float* __restrict__ gamma, const float* __restrict__ beta, float* __restrict__ outx){
    __shared__ float red[8];
    int row = blockIdx.x;
    int tid = threadIdx.x;
    float4 gv = *(const float4*)(glu + (size_t)row*H + tid*4);
    float4 rv = *(const float4*)(res + (size_t)row*H + tid*4);
    float x0=gv.x+rv.x, x1=gv.y+rv.y, x2=gv.z+rv.z, x3=gv.w+rv.w;
    float s = x0+x1+x2+x3;
    float q = x0*x0+x1*x1+x2*x2+x3*x3;
    #pragma unroll
    for (int m=32;m>=1;m>>=1){ s += __shfl_xor(s,m,64); q += __shfl_xor(q,m,64); }
    int wv = tid>>6;
    if ((tid&63)==0){ red[wv]=s; red[4+wv]=q; }
    __syncthreads();
    s = red[0]+red[1]+red[2]+red[3];
    q = red[4]+red[5]+red[6]+red[7];
    float m = s*(1.0f/H);
    float v = q*(1.0f/H) - m*m;
    float rstd = rsqrtf(v + 1e-5f);
    float4 gm = *(const float4*)(gamma + tid*4);
    float4 bt = *(const float4*)(beta + tid*4);
    float4 o;
    o.x = (x0-m)*rstd*gm.x + bt.x;
    o.y = (x1-m)*rstd*gm.y + bt.y;
    o.z = (x2-m)*rstd*gm.z + bt.z;
    o.w = (x3-m)*rstd*gm.w + bt.w;
    *(float4*)(outx + (size_t)row*H + tid*4) = o;
}

__global__ void k_ctx(const float* __restrict__ x, float* __restrict__ ctx){
    int i = blockIdx.x*256+threadIdx.x;
    int b = i>>10, h = i&(H-1);
    ctx[i] = x[((size_t)(b*TLEN + TLEN-1))*H + h];
}

// ======================= PERSISTENT DECODE =======================
// 256 blocks x 256 threads. Wave w owns h=w; lane = n; all 32 batches'
// states in registers; SSM params hoisted to registers (zero reloads).
#define FLAGSTRIDE 32
__device__ __forceinline__ void gbar(int* flags, int* rel, int g, int blk, int tid){
    __syncthreads();
    if (blk == 0){
        if (tid > 0){
            int it = 0;
            while (__hip_atomic_load(&flags[tid*FLAGSTRIDE], __ATOMIC_RELAXED,
                                     __HIP_MEMORY_SCOPE_AGENT) < g){
                __builtin_amdgcn_s_sleep(1);
                if (++it > 1000000) break;   // escape: wrong answer, not hang
            }
        }
        __syncthreads();
        if (tid == 0){
            __hip_atomic_store(rel, g, __ATOMIC_RELEASE, __HIP_MEMORY_SCOPE_AGENT);
            __builtin_amdgcn_fence(__ATOMIC_ACQUIRE, "agent");
        }
        __syncthreads();
    } else {
        if (tid == 0){
            __hip_atomic_store(&flags[blk*FLAGSTRIDE], g, __ATOMIC_RELEASE,
                               __HIP_MEMORY_SCOPE_AGENT);
            int it = 0;
            while (__hip_atomic_load(rel, __ATOMIC_RELAXED, __HIP_MEMORY_SCOPE_AGENT) < g){
                __builtin_amdgcn_s_sleep(1);
                if (++it > 1000000) break;
            }
            __builtin_amdgcn_fence(__ATOMIC_ACQUIRE, "agent");
        }
        __syncthreads();
    }
}

// decode GEMM phase: blocks 0..127, p = blk*8 + (tid>>5) in [0,1024), b = tid&31.
__device__ __forceinline__ void dec_gemm_p(int blk, int tid, float (*u_s)[260],
        const float* __restrict__ ygel, const float* __restrict__ Wdt,
        const float* __restrict__ b2, float* __restrict__ glud){
    int p = blk*8 + (tid>>5);
    int b = tid & 31;
    const float* wa = Wdt + (size_t)p*H;
    const float* wb = Wdt + (size_t)(p+1024)*H;
    float aa=0.f, ab=0.f;
    int row = tid & 31, cc = (tid>>5)*4;
    for (int kq=0; kq<4; kq++){
        __syncthreads();
        #pragma unroll
        for (int i=0;i<8;i++){
            int col = cc + i*32;
            *(float4*)&u_s[row][col] = *(const float4*)&ygel[row*H + kq*256 + col];
        }
        __syncthreads();
        const float* wak = wa + kq*256;
        const float* wbk = wb + kq*256;
        #pragma unroll 8
        for (int k=0;k<256;k+=8){
            float4 u0 = *(const float4*)&u_s[b][k];
            float4 u1 = *(const float4*)&u_s[b][k+4];
            float4 wa0 = *(const float4*)(wak + k);
            float4 wa1 = *(const float4*)(wak + k + 4);
            float4 wb0 = *(const float4*)(wbk + k);
            float4 wb1 = *(const float4*)(wbk + k + 4);
            aa = fmaf(u0.x,wa0.x, fmaf(u0.y,wa0.y, fmaf(u0.z,wa0.z, fmaf(u0.w,wa0.w, aa))));
            aa = fmaf(u1.x,wa1.x, fmaf(u1.y,wa1.y, fmaf(u1.z,wa1.z, fmaf(u1.w,wa1.w, aa))));
            ab = fmaf(u0.x,wb0.x, fmaf(u0.y,wb0.y, fmaf(u0.z,wb0.z, fmaf(u0.w,wb0.w, ab))));
            ab = fmaf(u1.x,wb1.x, fmaf(u1.y,wb1.y, fmaf(u1.z,wb1.z, fmaf(u1.w,wb1.w, ab))));
        }
    }
    glud[b*H + p] = (aa + b2[p]) * sigm_f(ab + b2[p+H]);
}

__device__ __forceinline__ void dec_ln_phase(int b, int tid, float* red,
        const float* __restrict__ glud, const float* __restrict__ gamma,
        const float* __restrict__ beta, float* __restrict__ decout,
        const float* __restrict__ ctx, const float* __restrict__ headw,
        const float* __restrict__ headb, float* __restrict__ bits,
        float* __restrict__ out, int step, int last){
    float4 gv = *(const float4*)(glud + (size_t)b*H + tid*4);
    float x0,x1,x2,x3;
    if (step==0){ x0=gv.x; x1=gv.y; x2=gv.z; x3=gv.w; }           // res = u0 = 0
    else        { x0=2.f*gv.x; x1=2.f*gv.y; x2=2.f*gv.z; x3=2.f*gv.w; }  // res = y
    float s = x0+x1+x2+x3, q = x0*x0+x1*x1+x2*x2+x3*x3;
    #pragma unroll
    for (int m=32;m>=1;m>>=1){ s+=__shfl_xor(s,m,64); q+=__shfl_xor(q,m,64); }
    int wv = tid>>6;
    if ((tid&63)==0){ red[wv]=s; red[4+wv]=q; }
    __syncthreads();
    s = red[0]+red[1]+red[2]+red[3];
    q = red[4]+red[5]+red[6]+red[7];
    float m = s*(1.f/H), v = q*(1.f/H)-m*m, rstd = rsqrtf(v+1e-5f);
    float4 gm = *(const float4*)(gamma + tid*4);
    float4 bt = *(const float4*)(beta + tid*4);
    float d0 = (x0-m)*rstd*gm.x+bt.x;
    float d1 = (x1-m)*rstd*gm.y+bt.y;
    float d2 = (x2-m)*rstd*gm.z+bt.z;
    float d3 = (x3-m)*rstd*gm.w+bt.w;
    if (!last){
        float4 o; o.x=d0;o.y=d1;o.z=d2;o.w=d3;
        *(float4*)(decout + (size_t)b*H + tid*4) = o;
    } else {
        float4 cv = *(const float4*)(ctx + (size_t)b*H + tid*4);
        d0+=cv.x; d1+=cv.y; d2+=cv.z; d3+=cv.w;
        float4 hw = *(const float4*)(headw + tid*4);
        float hp = d0*hw.x + d1*hw.y + d2*hw.z + d3*hw.w;
        #pragma unroll
        for (int mm=32;mm>=1;mm>>=1) hp += __shfl_xor(hp,mm,64);
        __syncthreads();
        if ((tid&63)==0) red[wv]=hp;
        __syncthreads();
        if (tid==0){
            float hs = red[0]+red[1]+red[2]+red[3] + headb[0];
            float bit = sigm_f(hs);
            bits[b] = bit;
            out[b*NSTEPS + step] = bit;
        }
    }
}

__global__ __launch_bounds__(256, 1) void k_decode(
        const float* __restrict__ dAr, const float* __restrict__ dAi,
        const float* __restrict__ dBr, const float* __restrict__ dBi,
        const float* __restrict__ Cre, const float* __restrict__ Cim,
        const float* __restrict__ Dv,
        const float* __restrict__ Wdt, const float* __restrict__ bias2,
        const float* __restrict__ lng, const float* __restrict__ lnb,
        const float* __restrict__ ctx, const float* __restrict__ headw,
        const float* __restrict__ headb,
        float* __restrict__ ygel, float* __restrict__ glud,
        float* __restrict__ dec, float* __restrict__ bits,
        float* __restrict__ out, int* __restrict__ barmem){
    __shared__ float u_s[32][260];
    __shared__ float scr[4][32][66];     // per-wave transpose scratch
    __shared__ float red[8];
    int blk = blockIdx.x, tid = threadIdx.x;
    int* flags = barmem;
    int* rel   = barmem + DECBLK*FLAGSTRIDE;
    int wv = tid >> 6, lane = tid & 63;
    int h = blk*4 + wv;                  // wave owns h; lane owns n=lane
    // hoist per-(h,n) params to registers (step-invariant)
    int p0 = h*NST + lane, p1 = (H+h)*NST + lane;
    float ar0=dAr[p0], ai0=dAi[p0], br0=dBr[p0], bi0=dBi[p0];
    float cr0=Cre[p0], ci0=Cim[p0];
    float ar1=dAr[p1], ai1=dAi[p1], br1=dBr[p1], bi1=dBi[p1];
    float cr1=Cre[p1], ci1=Cim[p1];
    float dv0 = Dv[h], dv1 = Dv[H+h];
    float s0r[32], s0i[32], s1r[32], s1i[32];
    #pragma unroll
    for (int j=0;j<32;j++){ s0r[j]=0.f; s0i[j]=0.f; s1r[j]=0.f; s1i[j]=0.f; }
    int g = 1;
    for (int step=0; step<NSTEPS; step++){
        // ---- layer 0 state: lane owns (h, n=lane, all 32 b)
        {
            float uvec = (step==0) ? 0.f : bits[lane & 31];
            #pragma unroll
            for (int b=0;b<32;b++){
                float ub = __shfl(uvec, b, 64);
                float nr = fmaf(ar0,s0r[b], fmaf(-ai0,s0i[b], br0*ub));
                float ni = fmaf(ai0,s0r[b], fmaf( ar0,s0i[b], bi0*ub));
                s0r[b]=nr; s0i[b]=ni;
                scr[wv][b][lane] = fmaf(cr0, nr, -ci0*ni);
            }
            __syncthreads();
            int b = lane & 31, half = lane >> 5;
            float s = 0.f;
            #pragma unroll
            for (int j=0;j<32;j++) s += scr[wv][b][half*32 + j];
            s += __shfl_xor(s, 32, 64);
            if (lane < 32) ygel[b*H + h] = gelu_f(fmaf(2.f, s, dv0*uvec));
            __syncthreads();
        }
        gbar(flags, rel, g++, blk, tid);
        if (blk < 128) dec_gemm_p(blk, tid, u_s, ygel, Wdt, bias2, glud);
        gbar(flags, rel, g++, blk, tid);
        if (blk < 32) dec_ln_phase(blk, tid, red, glud, lng, lnb, dec,
                                   ctx, headw, headb, bits, out, step, 0);
        gbar(flags, rel, g++, blk, tid);
        // ---- layer 1 state (u = dec[b*H + h])
        {
            float uvec = dec[(lane & 31)*H + h];
            #pragma unroll
            for (int b=0;b<32;b++){
                float ub = __shfl(uvec, b, 64);
                float nr = fmaf(ar1,s1r[b], fmaf(-ai1,s1i[b], br1*ub));
                float ni = fmaf(ai1,s1r[b], fmaf( ar1,s1i[b], bi1*ub));
                s1r[b]=nr; s1i[b]=ni;
                scr[wv][b][lane] = fmaf(cr1, nr, -ci1*ni);
            }
            __syncthreads();
            int b = lane & 31, half = lane >> 5;
            float s = 0.f;
            #pragma unroll
            for (int j=0;j<32;j++) s += scr[wv][b][half*32 + j];
            s += __shfl_xor(s, 32, 64);
            if (lane < 32) ygel[b*H + h] = gelu_f(fmaf(2.f, s, dv1*uvec));
            __syncthreads();
        }
        gbar(flags, rel, g++, blk, tid);
        if (blk < 128) dec_gemm_p(blk, tid, u_s, ygel, Wdt + (size_t)H2*H, bias2 + H2, glud);
        gbar(flags, rel, g++, blk, tid);
        if (blk < 32) dec_ln_phase(blk, tid, red, glud, lng+H, lnb+H, dec,
                                   ctx, headw, headb, bits, out, step, 1);
        gbar(flags, rel, g++, blk, tid);
    }
}

extern "C" void kernel_launch(void* const* d_in, const int* in_sizes, int n_in,
                              void* d_out, int out_size, void* d_ws, size_t ws_size,
                              hipStream_t stream) {
    const float* in_seq = (const float*)d_in[0];
    const float* inw  = (const float*)d_in[2];
    const float* inb  = (const float*)d_in[3];
    const float* log_dt = (const float*)d_in[4];
    const float* Are = (const float*)d_in[5];
    const float* Aim = (const float*)d_in[6];
    const float* Bre = (const float*)d_in[7];
    const float* Bim = (const float*)d_in[8];
    const float* Cre = (const float*)d_in[9];
    const float* Cim = (const float*)d_in[10];
    const float* Dv  = (const float*)d_in[11];
    const float* outw = (const float*)d_in[12];
    const float* outb = (const float*)d_in[13];
    const float* lng = (const float*)d_in[14];
    const float* lnb = (const float*)d_in[15];
    const float* headw = (const float*)d_in[16];
    const float* headb = (const float*)d_in[17];
    float* out = (float*)d_out;

    float* ws = (float*)d_ws;
    size_t off = 0;
    auto alloc = [&](size_t n){ float* p = ws + off; off += n; return p; };
    float* dAr = alloc((size_t)LAYN*H*NST);
    float* dAi = alloc((size_t)LAYN*H*NST);
    float* dBr = alloc((size_t)LAYN*H*NST);
    float* dBi = alloc((size_t)LAYN*H*NST);
    float* Kbuf = alloc((size_t)LAYN*H*TLEN);
    float* bufA = alloc((size_t)BSZ*TLEN*H);                              // 67MB
    float* bufB = alloc((size_t)BSZ*TLEN*H);                              // 67MB
    __hip_bfloat16* gbf = (__hip_bfloat16*)alloc((size_t)BSZ*TLEN*H/2);   // 33.5MB
    float* ctx = alloc((size_t)BSZ*H);
    float* sre = alloc((size_t)LAYN*BSZ*H*NST);                           // 16.8MB
    float* sim = alloc((size_t)LAYN*BSZ*H*NST);                           // 16.8MB
    __hip_bfloat16* Abf = (__hip_bfloat16*)sre;  // alias: Abf dead before decode
    __hip_bfloat16* Wt  = (__hip_bfloat16*)alloc((size_t)LAYN*H*H2/2);    // 8.4MB
    float* Wdt = alloc((size_t)LAYN*H2*H);                                // 16.8MB
    float* ygel = alloc((size_t)BSZ*H);
    float* glud = alloc((size_t)BSZ*H);
    float* dec  = alloc((size_t)BSZ*H);
    float* bits = alloc(64);
    int*   bar  = (int*)alloc(DECBLK*FLAGSTRIDE + 64);
    // total ~233 MB (round-3's proven 241.7 MB OK; round-4's 283.6 MB crashed)

    k_precompute<<<(LAYN*H*NST+255)/256, 256, 0, stream>>>(log_dt,Are,Aim,Bre,Bim,dAr,dAi,dBr,dBi);
    k_genK<<<LAYN*H, 64, 0, stream>>>(dAr,dAi,dBr,dBi,Cre,Cim,Kbuf);
    k_wtr<<<dim3(H2/32, H/32, LAYN), 256, 0, stream>>>(outw, Wt);
    k_wtrf<<<dim3(H2/32, H/32, LAYN), 256, 0, stream>>>(outw, Wdt);
    k_inproj_x <<<(BSZ*TLEN*H)/256, 256, 0, stream>>>(in_seq, inw, inb, bufA);
    k_inproj_xT<<<(BSZ*TLEN*H)/256, 256, 0, stream>>>(in_seq, inw, inb, bufB);

    // ---- layer 0: res = bufA (b,t,h); xT = bufB (b,h,t)
    k_conv<<<dim3(TLEN/CTT, H), 256, 0, stream>>>(bufB, Kbuf, Dv, gbf, 0);
    k_trcast_bf<<<dim3(TLEN/32, H/32, BSZ), 256, 0, stream>>>(gbf, Abf);
    k_gemm_glu_mfma<<<dim3(BSZ*TLEN/128, H/64), 256, 0, stream>>>(Abf, Wt, outb, bufB);
    k_ln<<<BSZ*TLEN, 256, 0, stream>>>(bufB, bufA, lng, lnb, bufA);
    {   // f32 transpose reuses k_trcast path: bufA (b,t,h) -> bufB (b,h,t)
        // (kept as separate kernel below)
    }
    // transpose f32
    {
        // declared below
    }
    // launch f32 transpose
    extern __global__ void k_transpose(const float*, float*);
    k_transpose<<<dim3(16,32,32), 256, 0, stream>>>(bufA, bufB);

    // ---- layer 1
    k_conv<<<dim3(TLEN/CTT, H), 256, 0, stream>>>(bufB, Kbuf, Dv, gbf, 1);
    k_trcast_bf<<<dim3(TLEN/32, H/32, BSZ), 256, 0, stream>>>(gbf, Abf);
    k_gemm_glu_mfma<<<dim3(BSZ*TLEN/128, H/64), 256, 0, stream>>>(Abf, Wt + (size_t)H*H2, outb + H2, bufB);
    k_ln<<<BSZ*TLEN, 256, 0, stream>>>(bufB, bufA, lng+H, lnb+H, bufA);

    k_ctx<<<(BSZ*H)/256, 256, 0, stream>>>(bufA, ctx);

    // ---- decode: one persistent kernel, 96 generation barriers
    hipMemsetAsync(bar, 0, sizeof(int)*(DECBLK*FLAGSTRIDE + 64), stream);
    k_decode<<<DECBLK, 256, 0, stream>>>(dAr,dAi,dBr,dBi,Cre,Cim,Dv,
                                         Wdt, outb, lng, lnb, ctx, headw, headb,
                                         ygel, glud, dec, bits, out, bar);
}

// ---------------- transpose (b,t,h) -> (b,h,t) f32 ----------------
__global__ __launch_bounds__(256) void k_transpose(const float* __restrict__ x, float* __restrict__ xT){
    __shared__ float tile[32][33];
    int t0 = blockIdx.x*32, h0 = blockIdx.y*32, b = blockIdx.z;
    int tx = threadIdx.x & 31, ty = threadIdx.x >> 5;
    #pragma unroll
    for (int i=0;i<32;i+=8)
        tile[ty+i][tx] = x[((size_t)(b*TLEN + t0+ty+i))*H + h0+tx];
    __syncthreads();
    #pragma unroll
    for (int i=0;i<32;i+=8)
        xT[((size_t)(b*H + h0+ty+i))*TLEN + t0+tx] = tile[tx][ty+i];
}

// Round 10
// 2406.130 us; speedup vs baseline: 1.6687x; 1.0084x over previous
//
#include <hip/hip_runtime.h>
#include <hip/hip_bf16.h>
#include <math.h>

#define H    1024
#define NST  64
#define LAYN 2
#define BSZ  32
#define TLEN 512
#define NSTEPS 16
#define H2   2048
#define DECBLK 256
#define FLAGSTRIDE 32
#define NREL 64

typedef __attribute__((ext_vector_type(8))) short bf16x8;
typedef __attribute__((ext_vector_type(4))) float f32x4;

__device__ __forceinline__ float gelu_f(float x){
    return 0.5f*x*(1.0f+erff(x*0.7071067811865475f));
}
__device__ __forceinline__ float sigm_f(float x){
    return 1.0f/(1.0f+expf(-x));
}
__device__ __forceinline__ short bfbits(float x){
    __hip_bfloat16 h = __float2bfloat16(x);
    return *(short*)&h;
}
__device__ __forceinline__ void gload16(const void* g, void* l){
    __builtin_amdgcn_global_load_lds((const __attribute__((address_space(1))) void*)g,
                                     (__attribute__((address_space(3))) void*)l, 16, 0, 0);
}

// ---------------- discretized SSM params ----------------
__global__ void k_precompute(const float* __restrict__ log_dt,
                             const float* __restrict__ Are, const float* __restrict__ Aim,
                             const float* __restrict__ Bre, const float* __restrict__ Bim,
                             float* __restrict__ dAr, float* __restrict__ dAi,
                             float* __restrict__ dBr, float* __restrict__ dBi){
    int i = blockIdx.x*256 + threadIdx.x;
    if (i >= LAYN*H*NST) return;
    int lh = i / NST;
    float dt = expf(log_dt[lh]);
    float ar = Are[i], ai = Aim[i];
    float e  = expf(dt*ar);
    float sa, ca; sincosf(dt*ai, &sa, &ca);
    float dar = e*ca, dai = e*sa;
    float zr = dar-1.0f, zi = dai;
    float inv = 1.0f/(ar*ar + ai*ai);
    float wr = (zr*ar + zi*ai)*inv;
    float wi = (zi*ar - zr*ai)*inv;
    float br = Bre[i], bi = Bim[i];
    dAr[i]=dar; dAi[i]=dai;
    dBr[i]=wr*br - wi*bi;
    dBi[i]=wr*bi + wi*br;
}

// ---------------- in_proj ----------------
__global__ void k_inproj_x(const float* __restrict__ in, const float* __restrict__ w,
                           const float* __restrict__ bias, float* __restrict__ x){
    int i = blockIdx.x*256+threadIdx.x;          // b*T*H + t*H + h
    int h = i & (H-1);
    int bt = i >> 10;
    x[i] = in[bt]*w[h] + bias[h];
}
__global__ void k_inproj_xT(const float* __restrict__ in, const float* __restrict__ w,
                            const float* __restrict__ bias, float* __restrict__ xT){
    int i = blockIdx.x*256+threadIdx.x;          // b*H*T + h*T + t
    int t = i & (TLEN-1);
    int bh = i >> 9;
    int h = bh & (H-1);
    int b = bh >> 10;
    xT[i] = in[b*TLEN + t]*w[h] + bias[h];
}

// ---------------- S4 conv kernel gen ----------------
__global__ __launch_bounds__(64) void k_genK(
        const float* __restrict__ dAr, const float* __restrict__ dAi,
        const float* __restrict__ dBr, const float* __restrict__ dBi,
        const float* __restrict__ Cre, const float* __restrict__ Cim,
        float* __restrict__ Kbuf){
    __shared__ float trans[16][65];
    int lh = blockIdx.x;
    int lane = threadIdx.x;
    int pi = lh*NST + lane;
    float ar=dAr[pi], ai=dAi[pi];
    float br=dBr[pi], bi=dBi[pi];
    float cr=2.f*Cre[pi], ci=2.f*Cim[pi];
    float wr = cr*br - ci*bi;
    float wi = cr*bi + ci*br;
    float* Krow = Kbuf + (size_t)lh*TLEN;
    int r = lane>>2, q = lane&3;
    for (int c=0;c<TLEN/16;c++){
        #pragma unroll
        for (int i=0;i<16;i++){
            trans[i][lane] = wr;
            float nr = fmaf(wr,ar, -wi*ai);
            float ni = fmaf(wr,ai,  wi*ar);
            wr=nr; wi=ni;
        }
        __syncthreads();
        float s = 0.f;
        #pragma unroll
        for (int m=0;m<16;m++) s += trans[r][q*16+m];
        s += __shfl_xor(s,1,64);
        s += __shfl_xor(s,2,64);
        if (q==0) Krow[c*16 + r] = s;
        __syncthreads();
    }
}

// ---------------- causal Toeplitz conv + D*u + gelu; bf16 (B,H,T) out ----------------
#define CTT 256
#define CJT 64
__global__ __launch_bounds__(256) void k_conv(
        const float* __restrict__ u,            // (B,H,T) f32
        const float* __restrict__ Kbuf,         // (L,H,T)
        const float* __restrict__ Dv,
        __hip_bfloat16* __restrict__ g,         // (B,H,T) bf16
        int layer){
    __shared__ float u_s[CJT][33];
    __shared__ float Ks[CTT+CJT];
    int h  = blockIdx.y;
    int t0 = blockIdx.x * CTT;
    int tid = threadIdx.x;
    int bg = tid & 7;
    int tg = tid >> 3;
    const float* Krow = Kbuf + ((size_t)layer*H + h)*TLEN;
    float acc[8][4];
    #pragma unroll
    for (int i=0;i<8;i++){
        #pragma unroll
        for (int b=0;b<4;b++) acc[i][b]=0.f;
    }
    int ntile = t0/CJT + CTT/CJT;
    for (int jt=0; jt<ntile; jt++){
        int j0 = jt*CJT;
        __syncthreads();
        for (int i=tid; i<CTT+CJT; i+=256){
            int d = t0 - j0 - (CJT-1) + i;
            Ks[i] = (d>=0) ? Krow[d] : 0.f;
        }
        {
            int jj = tid & 63, bq = tid >> 6;
            #pragma unroll
            for (int p=0;p<8;p++){
                int b = bq + p*4;
                u_s[jj][b] = u[((size_t)b*H + h)*TLEN + j0 + jj];
            }
        }
        __syncthreads();
        #pragma unroll 8
        for (int j=0;j<CJT;j++){
            float4 ub = *(const float4*)&u_s[j][bg*4];
            int base = tg*8 + (CJT-1) - j;
            float kv[8];
            #pragma unroll
            for (int i=0;i<8;i++) kv[i] = Ks[base+i];
            #pragma unroll
            for (int i=0;i<8;i++){
                acc[i][0] = fmaf(kv[i], ub.x, acc[i][0]);
                acc[i][1] = fmaf(kv[i], ub.y, acc[i][1]);
                acc[i][2] = fmaf(kv[i], ub.z, acc[i][2]);
                acc[i][3] = fmaf(kv[i], ub.w, acc[i][3]);
            }
        }
    }
    float dv = Dv[layer*H + h];
    int tb = t0 + tg*8;
    #pragma unroll
    for (int b=0;b<4;b++){
        int bb = bg*4 + b;
        const float* urow = u + ((size_t)bb*H + h)*TLEN + tb;
        float4 u0 = *(const float4*)urow;
        float4 u1 = *(const float4*)(urow+4);
        bf16x8 o;
        o[0] = bfbits(gelu_f(fmaf(dv,u0.x, acc[0][b])));
        o[1] = bfbits(gelu_f(fmaf(dv,u0.y, acc[1][b])));
        o[2] = bfbits(gelu_f(fmaf(dv,u0.z, acc[2][b])));
        o[3] = bfbits(gelu_f(fmaf(dv,u0.w, acc[3][b])));
        o[4] = bfbits(gelu_f(fmaf(dv,u1.x, acc[4][b])));
        o[5] = bfbits(gelu_f(fmaf(dv,u1.y, acc[5][b])));
        o[6] = bfbits(gelu_f(fmaf(dv,u1.z, acc[6][b])));
        o[7] = bfbits(gelu_f(fmaf(dv,u1.w, acc[7][b])));
        *(bf16x8*)(g + ((size_t)bb*H + h)*TLEN + tb) = o;
    }
}

// ---------------- bf16 transpose (B,H,T) -> (B,T,H) ----------------
__global__ __launch_bounds__(256) void k_trcast_bf(const __hip_bfloat16* __restrict__ x,
                                                   __hip_bfloat16* __restrict__ y){
    __shared__ __hip_bfloat16 tile[32][34];
    int t0 = blockIdx.x*32, h0 = blockIdx.y*32, b = blockIdx.z;
    int tx = threadIdx.x & 31, ty = threadIdx.x >> 5;
    #pragma unroll
    for (int i=0;i<32;i+=8)
        tile[ty+i][tx] = x[((size_t)(b*H + h0+ty+i))*TLEN + t0+tx];
    __syncthreads();
    #pragma unroll
    for (int i=0;i<32;i+=8)
        y[((size_t)(b*TLEN + t0+ty+i))*H + h0+tx] = tile[tx][ty+i];
}

// ---------------- transpose (b,t,h) -> (b,h,t) f32 ----------------
__global__ __launch_bounds__(256) void k_transpose(const float* __restrict__ x, float* __restrict__ xT){
    __shared__ float tile[32][33];
    int t0 = blockIdx.x*32, h0 = blockIdx.y*32, b = blockIdx.z;
    int tx = threadIdx.x & 31, ty = threadIdx.x >> 5;
    #pragma unroll
    for (int i=0;i<32;i+=8)
        tile[ty+i][tx] = x[((size_t)(b*TLEN + t0+ty+i))*H + h0+tx];
    __syncthreads();
    #pragma unroll
    for (int i=0;i<32;i+=8)
        xT[((size_t)(b*H + h0+ty+i))*TLEN + t0+tx] = tile[tx][ty+i];
}

// ---------------- W (L,H,2H) f32 -> Wt (L,2H,H) bf16 (encoder GEMM B operand) ----------------
__global__ __launch_bounds__(256) void k_wtr(const float* __restrict__ W,
                                             __hip_bfloat16* __restrict__ Wt){
    __shared__ float tile[32][33];
    int n0 = blockIdx.x*32, k0 = blockIdx.y*32, l = blockIdx.z;
    const float* Wl = W + (size_t)l*H*H2;
    __hip_bfloat16* Wtl = Wt + (size_t)l*H*H2;
    int tx = threadIdx.x & 31, ty = threadIdx.x >> 5;
    #pragma unroll
    for (int i=0;i<32;i+=8)
        tile[ty+i][tx] = Wl[(size_t)(k0+ty+i)*H2 + n0+tx];
    __syncthreads();
    #pragma unroll
    for (int i=0;i<32;i+=8)
        Wtl[(size_t)(n0+ty+i)*H + k0+tx] = __float2bfloat16(tile[tx][ty+i]);
}

// ---------------- W (L,H,2H) f32 -> Wdt (L,2H,H) f32 (decode GEMM rows) ----------------
__global__ __launch_bounds__(256) void k_wtrf(const float* __restrict__ W,
                                              float* __restrict__ Wdt){
    __shared__ float tile[32][33];
    int n0 = blockIdx.x*32, k0 = blockIdx.y*32, l = blockIdx.z;
    const float* Wl = W + (size_t)l*H*H2;
    float* Wo = Wdt + (size_t)l*H2*H;
    int tx = threadIdx.x & 31, ty = threadIdx.x >> 5;
    #pragma unroll
    for (int i=0;i<32;i+=8)
        tile[ty+i][tx] = Wl[(size_t)(k0+ty+i)*H2 + n0+tx];
    __syncthreads();
    #pragma unroll
    for (int i=0;i<32;i+=8)
        Wo[(size_t)(n0+ty+i)*H + k0+tx] = tile[tx][ty+i];
}

// ---------------- bf16 MFMA GEMM + bias + GLU fused (encoder) ----------------
__global__ __launch_bounds__(256) void k_gemm_glu_mfma(
        const __hip_bfloat16* __restrict__ Abf,
        const __hip_bfloat16* __restrict__ Wt,
        const float* __restrict__ bias2,         // (2048,)
        float* __restrict__ glu){                // (M,1024)
    __shared__ alignas(16) short As[128*32];
    __shared__ alignas(16) short Bs[128*32];
    const int K = 1024;
    int tid = threadIdx.x;
    int lane = tid & 63, wid = tid >> 6;
    int m0 = blockIdx.x * 128;
    int nb = blockIdx.y * 64;
    int g0 = tid, g1 = tid + 256;
    int r0 = g0 >> 2, r1 = g1 >> 2;
    int wtr0 = nb + ((r0>>6)<<5) + (r0&31) + ((r0>>5)&1)*1024;
    int wtr1 = nb + ((r1>>6)<<5) + (r1&31) + ((r1>>5)&1)*1024;
    const short* Ap = (const short*)Abf;
    const short* Bp = (const short*)Wt;
    const short* Ag0 = Ap + (size_t)(m0 + r0)*K + (g0&3)*8;
    const short* Ag1 = Ap + (size_t)(m0 + r1)*K + (g1&3)*8;
    const short* Bg0 = Bp + (size_t)wtr0*K + (g0&3)*8;
    const short* Bg1 = Bp + (size_t)wtr1*K + (g1&3)*8;
    char* AsB = (char*)As;
    char* BsB = (char*)Bs;
    int wr = wid >> 1, wc = wid & 1;
    int mo = wr*64, no = wc*64;
    f32x4 acc[4][4] = {};
    int arow = (lane & 15)*32 + (lane>>4)*8;
    for (int k0 = 0; k0 < K; k0 += 32){
        gload16(Ag0 + k0, AsB + wid*1024);
        gload16(Ag1 + k0, AsB + 4096 + wid*1024);
        gload16(Bg0 + k0, BsB + wid*1024);
        gload16(Bg1 + k0, BsB + 4096 + wid*1024);
        asm volatile("s_waitcnt vmcnt(0)" ::: "memory");
        __syncthreads();
        bf16x8 a[4], b[4];
        #pragma unroll
        for (int mi=0;mi<4;mi++)
            a[mi] = *(const bf16x8*)(As + (mo + mi*16)*32 + arow);
        #pragma unroll
        for (int ni=0;ni<4;ni++)
            b[ni] = *(const bf16x8*)(Bs + (no + ni*16)*32 + arow);
        #pragma unroll
        for (int mi=0;mi<4;mi++){
            #pragma unroll
            for (int ni=0;ni<4;ni++){
                acc[mi][ni] = __builtin_amdgcn_mfma_f32_16x16x32_bf16(a[mi], b[ni], acc[mi][ni], 0, 0, 0);
            }
        }
        __syncthreads();
    }
    int cbase = nb + wc*32 + (lane&15);
    #pragma unroll
    for (int ni=0;ni<2;ni++){
        int c = cbase + ni*16;
        float ba = bias2[c], bb = bias2[c+1024];
        #pragma unroll
        for (int mi=0;mi<4;mi++){
            #pragma unroll
            for (int r=0;r<4;r++){
                size_t m = m0 + mo + mi*16 + (lane>>4)*4 + r;
                float za = acc[mi][ni][r] + ba;
                float zb = acc[mi][ni+2][r] + bb;
                glu[m*H + c] = za * sigm_f(zb);
            }
        }
    }
}

// ---------------- LayerNorm over H per (b,t) row (encoder) ----------------
__global__ __launch_bounds__(256) void k_ln(const float* __restrict__ glu, const float* __restrict__ res,
        const float* __restrict__ gamma, const float* __restrict__ beta, float* __restrict__ outx){
    __shared__ float red[8];
    int row = blockIdx.x;
    int tid = threadIdx.x;
    float4 gv = *(const float4*)(glu + (size_t)row*H + tid*4);
    float4 rv = *(const float4*)(res + (size_t)row*H + tid*4);
    float x0=gv.x+rv.x, x1=gv.y+rv.y, x2=gv.z+rv.z, x3=gv.w+rv.w;
    float s = x0+x1+x2+x3;
    float q = x0*x0+x1*x1+x2*x2+x3*x3;
    #pragma unroll
    for (int m=32;m>=1;m>>=1){ s += __shfl_xor(s,m,64); q += __shfl_xor(q,m,64); }
    int wv = tid>>6;
    if ((tid&63)==0){ red[wv]=s; red[4+wv]=q; }
    __syncthreads();
    s = red[0]+red[1]+red[2]+red[3];
    q = red[4]+red[5]+red[6]+red[7];
    float m = s*(1.0f/H);
    float v = q*(1.0f/H) - m*m;
    float rstd = rsqrtf(v + 1e-5f);
    float4 gm = *(const float4*)(gamma + tid*4);
    float4 bt = *(const float4*)(beta + tid*4);
    float4 o;
    o.x = (x0-m)*rstd*gm.x + bt.x;
    o.y = (x1-m)*rstd*gm.y + bt.y;
    o.z = (x2-m)*rstd*gm.z + bt.z;
    o.w = (x3-m)*rstd*gm.w + bt.w;
    *(float4*)(outx + (size_t)row*H + tid*4) = o;
}

__global__ void k_ctx(const float* __restrict__ x, float* __restrict__ ctx){
    int i = blockIdx.x*256+threadIdx.x;
    int b = i>>10, h = i&(H-1);
    ctx[i] = x[((size_t)(b*TLEN + TLEN-1))*H + h];
}

// ======================= PERSISTENT DECODE =======================
// Generation barrier: per-block arrival flags (distinct lines) + 64 replicated
// release lines (<=4 pollers each). Blocks always ARRIVE (monotone flag) but
// only WAIT where they consume data.
__device__ __forceinline__ void gbar(int* flags, int* rel, int g, int blk, int tid, int wait){
    __syncthreads();
    if (blk == 0){
        if (tid > 0){
            int it = 0;
            while (__hip_atomic_load(&flags[tid*FLAGSTRIDE], __ATOMIC_RELAXED,
                                     __HIP_MEMORY_SCOPE_AGENT) < g){
                __builtin_amdgcn_s_sleep(1);
                if (++it > 1000000) break;   // escape: wrong answer, not hang
            }
        }
        __syncthreads();
        __builtin_amdgcn_fence(__ATOMIC_ACQUIRE, "agent");
        if (tid < NREL)
            __hip_atomic_store(&rel[tid*FLAGSTRIDE], g, __ATOMIC_RELEASE,
                               __HIP_MEMORY_SCOPE_AGENT);
        __syncthreads();
    } else {
        if (tid == 0){
            __hip_atomic_store(&flags[blk*FLAGSTRIDE], g, __ATOMIC_RELEASE,
                               __HIP_MEMORY_SCOPE_AGENT);
            if (wait){
                int* myrel = &rel[(blk & (NREL-1))*FLAGSTRIDE];
                int it = 0;
                while (__hip_atomic_load(myrel, __ATOMIC_RELAXED,
                                         __HIP_MEMORY_SCOPE_AGENT) < g){
                    __builtin_amdgcn_s_sleep(1);
                    if (++it > 1000000) break;
                }
                __builtin_amdgcn_fence(__ATOMIC_ACQUIRE, "agent");
            }
        }
        __syncthreads();
    }
}

// decode GEMM phase: blocks 0..127, p = blk*8 + (tid>>5) in [0,1024), b = tid&31.
__device__ __forceinline__ void dec_gemm_p(int blk, int tid, float (*u_s)[260],
        const float* __restrict__ ygel, const float* __restrict__ Wdt,
        const float* __restrict__ b2, float* __restrict__ glud){
    int p = blk*8 + (tid>>5);
    int b = tid & 31;
    const float* wa = Wdt + (size_t)p*H;
    const float* wb = Wdt + (size_t)(p+1024)*H;
    float aa=0.f, ab=0.f;
    int row = tid & 31, cc = (tid>>5)*4;
    for (int kq=0; kq<4; kq++){
        __syncthreads();
        #pragma unroll
        for (int i=0;i<8;i++){
            int col = cc + i*32;
            *(float4*)&u_s[row][col] = *(const float4*)&ygel[row*H + kq*256 + col];
        }
        __syncthreads();
        const float* wak = wa + kq*256;
        const float* wbk = wb + kq*256;
        #pragma unroll 8
        for (int k=0;k<256;k+=8){
            float4 u0 = *(const float4*)&u_s[b][k];
            float4 u1 = *(const float4*)&u_s[b][k+4];
            float4 wa0 = *(const float4*)(wak + k);
            float4 wa1 = *(const float4*)(wak + k + 4);
            float4 wb0 = *(const float4*)(wbk + k);
            float4 wb1 = *(const float4*)(wbk + k + 4);
            aa = fmaf(u0.x,wa0.x, fmaf(u0.y,wa0.y, fmaf(u0.z,wa0.z, fmaf(u0.w,wa0.w, aa))));
            aa = fmaf(u1.x,wa1.x, fmaf(u1.y,wa1.y, fmaf(u1.z,wa1.z, fmaf(u1.w,wa1.w, aa))));
            ab = fmaf(u0.x,wb0.x, fmaf(u0.y,wb0.y, fmaf(u0.z,wb0.z, fmaf(u0.w,wb0.w, ab))));
            ab = fmaf(u1.x,wb1.x, fmaf(u1.y,wb1.y, fmaf(u1.z,wb1.z, fmaf(u1.w,wb1.w, ab))));
        }
    }
    glud[b*H + p] = (aa + b2[p]) * sigm_f(ab + b2[p+H]);
}

__device__ __forceinline__ void dec_ln_phase(int b, int tid, float* red,
        const float* __restrict__ glud, const float* __restrict__ gamma,
        const float* __restrict__ beta, float* __restrict__ decout,
        const float* __restrict__ ctx, const float* __restrict__ headw,
        const float* __restrict__ headb, float* __restrict__ bits,
        float* __restrict__ out, int step, int last){
    float4 gv = *(const float4*)(glud + (size_t)b*H + tid*4);
    float x0,x1,x2,x3;
    if (step==0){ x0=gv.x; x1=gv.y; x2=gv.z; x3=gv.w; }           // res = u0 = 0
    else        { x0=2.f*gv.x; x1=2.f*gv.y; x2=2.f*gv.z; x3=2.f*gv.w; }  // res = y
    float s = x0+x1+x2+x3, q = x0*x0+x1*x1+x2*x2+x3*x3;
    #pragma unroll
    for (int m=32;m>=1;m>>=1){ s+=__shfl_xor(s,m,64); q+=__shfl_xor(q,m,64); }
    int wv = tid>>6;
    if ((tid&63)==0){ red[wv]=s; red[4+wv]=q; }
    __syncthreads();
    s = red[0]+red[1]+red[2]+red[3];
    q = red[4]+red[5]+red[6]+red[7];
    float m = s*(1.f/H), v = q*(1.f/H)-m*m, rstd = rsqrtf(v+1e-5f);
    float4 gm = *(const float4*)(gamma + tid*4);
    float4 bt = *(const float4*)(beta + tid*4);
    float d0 = (x0-m)*rstd*gm.x+bt.x;
    float d1 = (x1-m)*rstd*gm.y+bt.y;
    float d2 = (x2-m)*rstd*gm.z+bt.z;
    float d3 = (x3-m)*rstd*gm.w+bt.w;
    if (!last){
        float4 o; o.x=d0;o.y=d1;o.z=d2;o.w=d3;
        *(float4*)(decout + (size_t)b*H + tid*4) = o;
    } else {
        float4 cv = *(const float4*)(ctx + (size_t)b*H + tid*4);
        d0+=cv.x; d1+=cv.y; d2+=cv.z; d3+=cv.w;
        float4 hw = *(const float4*)(headw + tid*4);
        float hp = d0*hw.x + d1*hw.y + d2*hw.z + d3*hw.w;
        #pragma unroll
        for (int mm=32;mm>=1;mm>>=1) hp += __shfl_xor(hp,mm,64);
        __syncthreads();
        if ((tid&63)==0) red[wv]=hp;
        __syncthreads();
        if (tid==0){
            float hs = red[0]+red[1]+red[2]+red[3] + headb[0];
            float bit = sigm_f(hs);
            bits[b] = bit;
            out[b*NSTEPS + step] = bit;
        }
    }
}

__global__ __launch_bounds__(256, 1) void k_decode(
        const float* __restrict__ dAr, const float* __restrict__ dAi,
        const float* __restrict__ dBr, const float* __restrict__ dBi,
        const float* __restrict__ Cre, const float* __restrict__ Cim,
        const float* __restrict__ Dv,
        const float* __restrict__ Wdt, const float* __restrict__ bias2,
        const float* __restrict__ lng, const float* __restrict__ lnb,
        const float* __restrict__ ctx, const float* __restrict__ headw,
        const float* __restrict__ headb,
        float* __restrict__ ygel, float* __restrict__ glud,
        float* __restrict__ dec, float* __restrict__ bits,
        float* __restrict__ out, int* __restrict__ barmem){
    __shared__ float u_s[32][260];
    __shared__ float scr[4][32][66];     // per-wave transpose scratch
    __shared__ float red[8];
    int blk = blockIdx.x, tid = threadIdx.x;
    int* flags = barmem;
    int* rel   = barmem + DECBLK*FLAGSTRIDE;
    int wv = tid >> 6, lane = tid & 63;
    int h = blk*4 + wv;                  // wave owns h; lane owns n=lane
    int p0 = h*NST + lane, p1 = (H+h)*NST + lane;
    float ar0=dAr[p0], ai0=dAi[p0], br0=dBr[p0], bi0=dBi[p0];
    float cr0=Cre[p0], ci0=Cim[p0];
    float ar1=dAr[p1], ai1=dAi[p1], br1=dBr[p1], bi1=dBi[p1];
    float cr1=Cre[p1], ci1=Cim[p1];
    float dv0 = Dv[h], dv1 = Dv[H+h];
    float s0r[32], s0i[32], s1r[32], s1i[32];
    #pragma unroll
    for (int j=0;j<32;j++){ s0r[j]=0.f; s0i[j]=0.f; s1r[j]=0.f; s1i[j]=0.f; }
    int g = 1;
    for (int step=0; step<NSTEPS; step++){
        // ---- layer 0 state: lane owns (h, n=lane, all 32 b)
        {
            float uvec = (step==0) ? 0.f : bits[lane & 31];
            #pragma unroll
            for (int b=0;b<32;b++){
                float ub = __shfl(uvec, b, 64);
                float nr = fmaf(ar0,s0r[b], fmaf(-ai0,s0i[b], br0*ub));
                float ni = fmaf(ai0,s0r[b], fmaf( ar0,s0i[b], bi0*ub));
                s0r[b]=nr; s0i[b]=ni;
                scr[wv][b][lane] = fmaf(cr0, nr, -ci0*ni);
            }
            __syncthreads();
            int b = lane & 31, half = lane >> 5;
            float s = 0.f;
            #pragma unroll
            for (int j=0;j<32;j++) s += scr[wv][b][half*32 + j];
            s += __shfl_xor(s, 32, 64);
            if (lane < 32) ygel[b*H + h] = gelu_f(fmaf(2.f, s, dv0*uvec));
            __syncthreads();
        }
        gbar(flags, rel, g++, blk, tid, blk < 128);    // B1: GEMM needs ygel
        if (blk < 128) dec_gemm_p(blk, tid, u_s, ygel, Wdt, bias2, glud);
        gbar(flags, rel, g++, blk, tid, blk < 32);     // B2: LN needs glud
        if (blk < 32) dec_ln_phase(blk, tid, red, glud, lng, lnb, dec,
                                   ctx, headw, headb, bits, out, step, 0);
        gbar(flags, rel, g++, blk, tid, 1);            // B3: all need dec
        // ---- layer 1 state (u = dec[b*H + h])
        {
            float uvec = dec[(lane & 31)*H + h];
            #pragma unroll
            for (int b=0;b<32;b++){
                float ub = __shfl(uvec, b, 64);
                float nr = fmaf(ar1,s1r[b], fmaf(-ai1,s1i[b], br1*ub));
                float ni = fmaf(ai1,s1r[b], fmaf( ar1,s1i[b], bi1*ub));
                s1r[b]=nr; s1i[b]=ni;
                scr[wv][b][lane] = fmaf(cr1, nr, -ci1*ni);
            }
            __syncthreads();
            int b = lane & 31, half = lane >> 5;
            float s = 0.f;
            #pragma unroll
            for (int j=0;j<32;j++) s += scr[wv][b][half*32 + j];
            s += __shfl_xor(s, 32, 64);
            if (lane < 32) ygel[b*H + h] = gelu_f(fmaf(2.f, s, dv1*uvec));
            __syncthreads();
        }
        gbar(flags, rel, g++, blk, tid, blk < 128);    // B4
        if (blk < 128) dec_gemm_p(blk, tid, u_s, ygel, Wdt + (size_t)H2*H, bias2 + H2, glud);
        gbar(flags, rel, g++, blk, tid, blk < 32);     // B5
        if (blk < 32) dec_ln_phase(blk, tid, red, glud, lng+H, lnb+H, dec,
                                   ctx, headw, headb, bits, out, step, 1);
        if (step < NSTEPS-1)
            gbar(flags, rel, g++, blk, tid, 1);        // B6: all need bits (skip last)
    }
}

extern "C" void kernel_launch(void* const* d_in, const int* in_sizes, int n_in,
                              void* d_out, int out_size, void* d_ws, size_t ws_size,
                              hipStream_t stream) {
    const float* in_seq = (const float*)d_in[0];
    const float* inw  = (const float*)d_in[2];
    const float* inb  = (const float*)d_in[3];
    const float* log_dt = (const float*)d_in[4];
    const float* Are = (const float*)d_in[5];
    const float* Aim = (const float*)d_in[6];
    const float* Bre = (const float*)d_in[7];
    const float* Bim = (const float*)d_in[8];
    const float* Cre = (const float*)d_in[9];
    const float* Cim = (const float*)d_in[10];
    const float* Dv  = (const float*)d_in[11];
    const float* outw = (const float*)d_in[12];
    const float* outb = (const float*)d_in[13];
    const float* lng = (const float*)d_in[14];
    const float* lnb = (const float*)d_in[15];
    const float* headw = (const float*)d_in[16];
    const float* headb = (const float*)d_in[17];
    float* out = (float*)d_out;

    float* ws = (float*)d_ws;
    size_t off = 0;
    auto alloc = [&](size_t n){ float* p = ws + off; off += n; return p; };
    float* dAr = alloc((size_t)LAYN*H*NST);
    float* dAi = alloc((size_t)LAYN*H*NST);
    float* dBr = alloc((size_t)LAYN*H*NST);
    float* dBi = alloc((size_t)LAYN*H*NST);
    float* Kbuf = alloc((size_t)LAYN*H*TLEN);
    float* bufA = alloc((size_t)BSZ*TLEN*H);                              // 67MB
    float* bufB = alloc((size_t)BSZ*TLEN*H);                              // 67MB
    __hip_bfloat16* gbf = (__hip_bfloat16*)alloc((size_t)BSZ*TLEN*H/2);   // 33.5MB
    float* ctx = alloc((size_t)BSZ*H);
    float* sre = alloc((size_t)LAYN*BSZ*H*NST);                           // 16.8MB
    float* sim = alloc((size_t)LAYN*BSZ*H*NST);                           // 16.8MB
    __hip_bfloat16* Abf = (__hip_bfloat16*)sre;  // alias: Abf dead before decode
    __hip_bfloat16* Wt  = (__hip_bfloat16*)alloc((size_t)LAYN*H*H2/2);    // 8.4MB
    float* Wdt = alloc((size_t)LAYN*H2*H);                                // 16.8MB
    float* ygel = alloc((size_t)BSZ*H);
    float* glud = alloc((size_t)BSZ*H);
    float* dec  = alloc((size_t)BSZ*H);
    float* bits = alloc(64);
    int*   bar  = (int*)alloc((DECBLK + NREL)*FLAGSTRIDE);
    // total ~233 MB (round-3's proven 241.7 MB OK; round-4's 283.6 MB crashed)

    k_precompute<<<(LAYN*H*NST+255)/256, 256, 0, stream>>>(log_dt,Are,Aim,Bre,Bim,dAr,dAi,dBr,dBi);
    k_genK<<<LAYN*H, 64, 0, stream>>>(dAr,dAi,dBr,dBi,Cre,Cim,Kbuf);
    k_wtr<<<dim3(H2/32, H/32, LAYN), 256, 0, stream>>>(outw, Wt);
    k_wtrf<<<dim3(H2/32, H/32, LAYN), 256, 0, stream>>>(outw, Wdt);
    k_inproj_x <<<(BSZ*TLEN*H)/256, 256, 0, stream>>>(in_seq, inw, inb, bufA);
    k_inproj_xT<<<(BSZ*TLEN*H)/256, 256, 0, stream>>>(in_seq, inw, inb, bufB);

    // ---- layer 0: res = bufA (b,t,h); xT = bufB (b,h,t)
    k_conv<<<dim3(TLEN/CTT, H), 256, 0, stream>>>(bufB, Kbuf, Dv, gbf, 0);
    k_trcast_bf<<<dim3(TLEN/32, H/32, BSZ), 256, 0, stream>>>(gbf, Abf);
    k_gemm_glu_mfma<<<dim3(BSZ*TLEN/128, H/64), 256, 0, stream>>>(Abf, Wt, outb, bufB);
    k_ln<<<BSZ*TLEN, 256, 0, stream>>>(bufB, bufA, lng, lnb, bufA);
    k_transpose<<<dim3(16,32,32), 256, 0, stream>>>(bufA, bufB);

    // ---- layer 1
    k_conv<<<dim3(TLEN/CTT, H), 256, 0, stream>>>(bufB, Kbuf, Dv, gbf, 1);
    k_trcast_bf<<<dim3(TLEN/32, H/32, BSZ), 256, 0, stream>>>(gbf, Abf);
    k_gemm_glu_mfma<<<dim3(BSZ*TLEN/128, H/64), 256, 0, stream>>>(Abf, Wt + (size_t)H*H2, outb + H2, bufB);
    k_ln<<<BSZ*TLEN, 256, 0, stream>>>(bufB, bufA, lng+H, lnb+H, bufA);

    k_ctx<<<(BSZ*H)/256, 256, 0, stream>>>(bufA, ctx);

    // ---- decode: one persistent kernel, generation barriers
    hipMemsetAsync(bar, 0, sizeof(int)*(DECBLK + NREL)*FLAGSTRIDE, stream);
    k_decode<<<DECBLK, 256, 0, stream>>>(dAr,dAi,dBr,dBi,Cre,Cim,Dv,
                                         Wdt, outb, lng, lnb, ctx, headw, headb,
                                         ygel, glud, dec, bits, out, bar);
}